// Round 2
// baseline (4741.493 us; speedup 1.0000x reference)
//
#include <hip/hip_runtime.h>
#include <hip/hip_bf16.h>
#include <math.h>

// GatedAttention, fp32 correctness-first pipeline.
// Shapes: B=8, C=128, H=W=64, P=4096; imgs [8,3,256,256], masks [8,1,256,256].
//
// Stage 1: gate conv stack (reflect-pad convs, fp32 direct, relu), then
//          gate = tan(PI*(tanh(relu(conv5))-0.5)).  fp32 mandatory: dgate/ds ~ 1/(pi s^2).
// Stage 2: invn[p] = 1/||F[:,p]+1e-7||;  scores[p][q] = invn[p]*sum_c (F[c,p]+eps)F[c,q] + gate[p]
// Stage 3: column softmax stats (m,l) over p; att = K^T @ exp(scores-m) (split-K=2 partials)
// Stage 4: combiner 1x1: out = cw[:, :C]*att*invl + cw[:, C:]*F + cb
//
// R1 fix: scores_k was called with `gate + b*4096` but indexes gate[b*4096 + p]
// internally -> double offset, wrong/OOB gate for b>0. Pass base pointer.

#define PI_F 3.1415926f

// ---------------- conv1: [8,4,256,256] -> [8,32,256,256], K7 S1 P3, relu --------------
__global__ __launch_bounds__(256) void conv1_k(
    const float* __restrict__ imgs, const float* __restrict__ masks,
    const float* __restrict__ w, const float* __restrict__ bias,
    float* __restrict__ out)
{
    const int tx = threadIdx.x & 63, ty = threadIdx.x >> 6;
    const int ox = blockIdx.x * 64 + tx;
    const int oy = blockIdx.y * 4 + ty;
    const int ocg = blockIdx.z & 7, b = blockIdx.z >> 3;
    const int oc0 = ocg << 2;
    int ixo[7], iyo[7];
#pragma unroll
    for (int k = 0; k < 7; ++k) {
        int ix = ox + k - 3; if (ix < 0) ix = -ix; if (ix >= 256) ix = 510 - ix;
        int iy = oy + k - 3; if (iy < 0) iy = -iy; if (iy >= 256) iy = 510 - iy;
        ixo[k] = ix; iyo[k] = iy << 8;
    }
    float a0 = bias[oc0], a1 = bias[oc0 + 1], a2 = bias[oc0 + 2], a3 = bias[oc0 + 3];
    const int HW = 65536;
#pragma unroll
    for (int ic = 0; ic < 4; ++ic) {
        const float* inc = (ic < 3) ? (imgs + (b * 3 + ic) * HW) : (masks + b * HW);
        const float* wc = w + (oc0 * 4 + ic) * 49;   // w: [32][4][7][7], cs = 196
#pragma unroll
        for (int ky = 0; ky < 7; ++ky) {
            const float* row = inc + iyo[ky];
#pragma unroll
            for (int kx = 0; kx < 7; ++kx) {
                float v = row[ixo[kx]];
                a0 = fmaf(wc[ky * 7 + kx], v, a0);
                a1 = fmaf(wc[196 + ky * 7 + kx], v, a1);
                a2 = fmaf(wc[392 + ky * 7 + kx], v, a2);
                a3 = fmaf(wc[588 + ky * 7 + kx], v, a3);
            }
        }
    }
    long ob = ((long)(b * 32 + oc0) << 16) + (oy << 8) + ox;
    out[ob]          = fmaxf(a0, 0.f);
    out[ob + 65536]  = fmaxf(a1, 0.f);
    out[ob + 131072] = fmaxf(a2, 0.f);
    out[ob + 196608] = fmaxf(a3, 0.f);
}

// ---------------- generic reflect conv, 4 oc/thread, relu ----------------
template<int K, int S, int PAD>
__global__ __launch_bounds__(256) void conv_k(
    const float* __restrict__ in, const float* __restrict__ w,
    const float* __restrict__ bias, float* __restrict__ out,
    int Cin, int Cout, int Hin, int Win, int Hout, int Wout)
{
    const int tx = threadIdx.x & 63, ty = threadIdx.x >> 6;
    const int ox = blockIdx.x * 64 + tx;
    const int oy = blockIdx.y * 4 + ty;
    const int ng = Cout >> 2;
    const int ocg = blockIdx.z % ng, b = blockIdx.z / ng;
    const int oc0 = ocg << 2;
    int ixo[K], iyo[K];
#pragma unroll
    for (int k = 0; k < K; ++k) {
        int ix = ox * S + k - PAD; if (ix < 0) ix = -ix; if (ix >= Win) ix = 2 * Win - 2 - ix;
        int iy = oy * S + k - PAD; if (iy < 0) iy = -iy; if (iy >= Hin) iy = 2 * Hin - 2 - iy;
        ixo[k] = ix; iyo[k] = iy * Win;
    }
    float a0 = bias[oc0], a1 = bias[oc0 + 1], a2 = bias[oc0 + 2], a3 = bias[oc0 + 3];
    const int HW = Hin * Win;
    const int KK = K * K;
    const int cs = Cin * KK;
    const float* inb = in + (long)b * Cin * HW;
    const float* wb = w + (long)oc0 * cs;
    for (int ic = 0; ic < Cin; ++ic) {
        const float* inc = inb + ic * HW;
        const float* wc = wb + ic * KK;
#pragma unroll
        for (int ky = 0; ky < K; ++ky) {
            const float* row = inc + iyo[ky];
#pragma unroll
            for (int kx = 0; kx < K; ++kx) {
                float v = row[ixo[kx]];
                a0 = fmaf(wc[ky * K + kx], v, a0);
                a1 = fmaf(wc[cs + ky * K + kx], v, a1);
                a2 = fmaf(wc[2 * cs + ky * K + kx], v, a2);
                a3 = fmaf(wc[3 * cs + ky * K + kx], v, a3);
            }
        }
    }
    long ob = ((long)(b * Cout + oc0) * Hout + oy) * Wout + ox;
    long oHW = (long)Hout * Wout;
    out[ob]           = fmaxf(a0, 0.f);
    out[ob + oHW]     = fmaxf(a1, 0.f);
    out[ob + 2 * oHW] = fmaxf(a2, 0.f);
    out[ob + 3 * oHW] = fmaxf(a3, 0.f);
}

// ---------------- conv5 (256->1, K3 S1 P1) + relu + gate transform ----------------
__global__ __launch_bounds__(256) void conv5_gate_k(
    const float* __restrict__ s4, const float* __restrict__ w,
    const float* __restrict__ bias, float* __restrict__ gate)
{
    const int tid = threadIdx.x;
    const int p = blockIdx.x * 256 + tid;
    const int b = blockIdx.y;
    const int oy = p >> 6, ox = p & 63;
    int ixo[3], iyo[3];
#pragma unroll
    for (int k = 0; k < 3; ++k) {
        int ix = ox + k - 1; if (ix < 0) ix = -ix; if (ix >= 64) ix = 126 - ix;
        int iy = oy + k - 1; if (iy < 0) iy = -iy; if (iy >= 64) iy = 126 - iy;
        ixo[k] = ix; iyo[k] = iy << 6;
    }
    float acc = bias[0];
    const float* inb = s4 + (long)b * 256 * 4096;
    for (int ic = 0; ic < 256; ++ic) {
        const float* inc = inb + ic * 4096;
        const float* wc = w + ic * 9;
#pragma unroll
        for (int ky = 0; ky < 3; ++ky)
#pragma unroll
            for (int kx = 0; kx < 3; ++kx)
                acc = fmaf(wc[ky * 3 + kx], inc[iyo[ky] + ixo[kx]], acc);
    }
    float s = fmaxf(acc, 0.f);
    gate[(b << 12) + p] = tanf(PI_F * (tanhf(s) - 0.5f));
}

// ---------------- invn[b][p] = 1/sqrt(sum_c (F+1e-7)^2) ----------------
__global__ __launch_bounds__(256) void invn_k(const float* __restrict__ F, float* __restrict__ invn)
{
    const int p = blockIdx.x * 256 + threadIdx.x;
    const int b = blockIdx.y;
    const float* Fb = F + (long)b * 524288;
    float ss = 0.f;
#pragma unroll 8
    for (int c = 0; c < 128; ++c) {
        float v = Fb[c * 4096 + p] + 1e-7f;
        ss = fmaf(v, v, ss);
    }
    invn[(b << 12) + p] = 1.0f / sqrtf(ss);
}

// ---------------- scores[p][q] = invn[p]*sum_c (F[c,p]+eps)F[c,q] + gate[p] ----------
__global__ __launch_bounds__(256) void scores_k(
    const float* __restrict__ F, const float* __restrict__ invn,
    const float* __restrict__ gate, float* __restrict__ scores, int b)
{
    __shared__ float As[16][64];
    __shared__ float Bs[16][64];
    const int tid = threadIdx.x;
    const int tx = tid & 15, ty = tid >> 4;
    const int p0 = blockIdx.y << 6, q0 = blockIdx.x << 6;
    const float* Fb = F + (long)b * 524288;
    float acc[4][4] = {};
    const int lr = tid >> 4, lc = (tid & 15) << 2;
    for (int k0 = 0; k0 < 128; k0 += 16) {
        float4 av = *(const float4*)&Fb[(k0 + lr) * 4096 + p0 + lc];
        float4 bv = *(const float4*)&Fb[(k0 + lr) * 4096 + q0 + lc];
        av.x += 1e-7f; av.y += 1e-7f; av.z += 1e-7f; av.w += 1e-7f;
        *(float4*)&As[lr][lc] = av;
        *(float4*)&Bs[lr][lc] = bv;
        __syncthreads();
#pragma unroll
        for (int kk = 0; kk < 16; ++kk) {
            float4 a = *(const float4*)&As[kk][tx << 2];
            float4 bq = *(const float4*)&Bs[kk][ty << 2];
            acc[0][0] = fmaf(a.x, bq.x, acc[0][0]); acc[0][1] = fmaf(a.x, bq.y, acc[0][1]);
            acc[0][2] = fmaf(a.x, bq.z, acc[0][2]); acc[0][3] = fmaf(a.x, bq.w, acc[0][3]);
            acc[1][0] = fmaf(a.y, bq.x, acc[1][0]); acc[1][1] = fmaf(a.y, bq.y, acc[1][1]);
            acc[1][2] = fmaf(a.y, bq.z, acc[1][2]); acc[1][3] = fmaf(a.y, bq.w, acc[1][3]);
            acc[2][0] = fmaf(a.z, bq.x, acc[2][0]); acc[2][1] = fmaf(a.z, bq.y, acc[2][1]);
            acc[2][2] = fmaf(a.z, bq.z, acc[2][2]); acc[2][3] = fmaf(a.z, bq.w, acc[2][3]);
            acc[3][0] = fmaf(a.w, bq.x, acc[3][0]); acc[3][1] = fmaf(a.w, bq.y, acc[3][1]);
            acc[3][2] = fmaf(a.w, bq.z, acc[3][2]); acc[3][3] = fmaf(a.w, bq.w, acc[3][3]);
        }
        __syncthreads();
    }
    const int bp = b << 12;
#pragma unroll
    for (int i = 0; i < 4; ++i) {
        int p = p0 + (tx << 2) + i;
        float sc = invn[bp + p], g = gate[bp + p];
        float4 o;
        o.x = fmaf(acc[i][0], sc, g);
        o.y = fmaf(acc[i][1], sc, g);
        o.z = fmaf(acc[i][2], sc, g);
        o.w = fmaf(acc[i][3], sc, g);
        *(float4*)&scores[(long)p * 4096 + q0 + (ty << 2)] = o;
    }
}

// ---------------- softmax stats over p (columns of scores) ----------------
__global__ __launch_bounds__(256) void stats_part_k(
    const float* __restrict__ scores, float* __restrict__ pm, float* __restrict__ pl)
{
    const int q = blockIdx.x * 256 + threadIdx.x;
    const int pc = blockIdx.y;                 // 32 chunks x 128 rows
    float m = -3.4e38f, l = 0.f;
    const float* s = scores + (long)pc * 128 * 4096 + q;
    for (int r = 0; r < 128; ++r) {
        float x = s[(long)r * 4096];
        if (x > m) { l = l * __expf(m - x) + 1.f; m = x; }
        else l += __expf(x - m);
    }
    pm[pc * 4096 + q] = m;
    pl[pc * 4096 + q] = l;
}

__global__ __launch_bounds__(256) void stats_comb_k(
    const float* __restrict__ pm, const float* __restrict__ pl,
    float* __restrict__ mq, float* __restrict__ invl)
{
    const int q = blockIdx.x * 256 + threadIdx.x;
    float m = -3.4e38f;
#pragma unroll
    for (int i = 0; i < 32; ++i) m = fmaxf(m, pm[i * 4096 + q]);
    float l = 0.f;
#pragma unroll
    for (int i = 0; i < 32; ++i) l += pl[i * 4096 + q] * __expf(pm[i * 4096 + q] - m);
    mq[q] = m;
    invl[q] = 1.0f / l;
}

// ------- att partials: attP[ks][c][q] = sum_{p in ks-half} exp(s[p][q]-m[q])*(F[c,p]+eps)
__global__ __launch_bounds__(256) void attv_k(
    const float* __restrict__ scores, const float* __restrict__ F,
    const float* __restrict__ mq, float* __restrict__ attP, int b)
{
    __shared__ float Ks[32][64];   // [p][c]
    __shared__ float Es[32][32];   // [p][q], exp applied
    __shared__ float Ms[32];
    const int tid = threadIdx.x;
    const int tx = tid & 15, ty = tid >> 4;
    const int q0 = blockIdx.x << 5;          // 128 q-blocks
    const int c0 = blockIdx.y << 6;          // 2 c-halves
    const int ks = blockIdx.z;               // split-K = 2
    if (tid < 32) Ms[tid] = mq[q0 + tid];
    __syncthreads();
    const float* Fb = F + (long)b * 524288;
    float acc[4][2] = {};
    const int cc = tid >> 2, ps = (tid & 3) << 3;
    const int qq = tid & 31, pr = tid >> 5;
    const int pend = ks * 2048 + 2048;
    for (int p0 = ks * 2048; p0 < pend; p0 += 32) {
        float4 v0 = *(const float4*)&Fb[(long)(c0 + cc) * 4096 + p0 + ps];
        float4 v1 = *(const float4*)&Fb[(long)(c0 + cc) * 4096 + p0 + ps + 4];
        Ks[ps + 0][cc] = v0.x + 1e-7f;
        Ks[ps + 1][cc] = v0.y + 1e-7f;
        Ks[ps + 2][cc] = v0.z + 1e-7f;
        Ks[ps + 3][cc] = v0.w + 1e-7f;
        Ks[ps + 4][cc] = v1.x + 1e-7f;
        Ks[ps + 5][cc] = v1.y + 1e-7f;
        Ks[ps + 6][cc] = v1.z + 1e-7f;
        Ks[ps + 7][cc] = v1.w + 1e-7f;
        float m = Ms[qq];
#pragma unroll
        for (int i = 0; i < 4; ++i) {
            int pp = pr + (i << 3);
            Es[pp][qq] = __expf(scores[(long)(p0 + pp) * 4096 + q0 + qq] - m);
        }
        __syncthreads();
#pragma unroll
        for (int kk = 0; kk < 32; ++kk) {
            float4 a = *(const float4*)&Ks[kk][tx << 2];
            float2 e = *(const float2*)&Es[kk][ty << 1];
            acc[0][0] = fmaf(a.x, e.x, acc[0][0]); acc[0][1] = fmaf(a.x, e.y, acc[0][1]);
            acc[1][0] = fmaf(a.y, e.x, acc[1][0]); acc[1][1] = fmaf(a.y, e.y, acc[1][1]);
            acc[2][0] = fmaf(a.z, e.x, acc[2][0]); acc[2][1] = fmaf(a.z, e.y, acc[2][1]);
            acc[3][0] = fmaf(a.w, e.x, acc[3][0]); acc[3][1] = fmaf(a.w, e.y, acc[3][1]);
        }
        __syncthreads();
    }
    float* ap = attP + (long)(b * 2 + ks) * 128 * 4096;
#pragma unroll
    for (int i = 0; i < 4; ++i) {
        int c = c0 + (tx << 2) + i;
        int q = q0 + (ty << 1);
        ap[(long)c * 4096 + q]     = acc[i][0];
        ap[(long)c * 4096 + q + 1] = acc[i][1];
    }
}

// ---------------- combiner: out = cw[:, :128]*(att*invl) + cw[:, 128:]*F + cb --------
__global__ __launch_bounds__(256) void combiner_k(
    const float* __restrict__ attP, const float* __restrict__ F,
    const float* __restrict__ invl, const float* __restrict__ cw,
    const float* __restrict__ cb, float* __restrict__ out)
{
    const int tid = threadIdx.x;
    const int q = blockIdx.x * 256 + tid;
    const int o0 = blockIdx.y << 4;
    const int b = blockIdx.z;
    float il = invl[(b << 12) + q];
    const float* A0 = attP + (long)(b * 2 + 0) * 128 * 4096 + q;
    const float* A1 = attP + (long)(b * 2 + 1) * 128 * 4096 + q;
    const float* Fb = F + (long)b * 524288 + q;
    float acc[16];
#pragma unroll
    for (int j = 0; j < 16; ++j) acc[j] = cb[o0 + j];
    for (int c = 0; c < 128; ++c) {
        float a = (A0[(long)c * 4096] + A1[(long)c * 4096]) * il;
        float f = Fb[(long)c * 4096];
#pragma unroll
        for (int j = 0; j < 16; ++j) {
            acc[j] = fmaf(cw[(o0 + j) * 256 + c], a, acc[j]);
            acc[j] = fmaf(cw[(o0 + j) * 256 + 128 + c], f, acc[j]);
        }
    }
#pragma unroll
    for (int j = 0; j < 16; ++j)
        out[((long)(b * 128 + o0 + j) << 12) + q] = acc[j];
}

// =====================================================================================
extern "C" void kernel_launch(void* const* d_in, const int* in_sizes, int n_in,
                              void* d_out, int out_size, void* d_ws, size_t ws_size,
                              hipStream_t stream)
{
    const float* F     = (const float*)d_in[0];   // feature_in [8,128,64,64]
    const float* imgs  = (const float*)d_in[1];   // [8,3,256,256]
    const float* masks = (const float*)d_in[2];   // [8,1,256,256]
    const float* gw1 = (const float*)d_in[3];  const float* gb1 = (const float*)d_in[4];
    const float* gw2 = (const float*)d_in[5];  const float* gb2 = (const float*)d_in[6];
    const float* gw3 = (const float*)d_in[7];  const float* gb3 = (const float*)d_in[8];
    const float* gw4 = (const float*)d_in[9];  const float* gb4 = (const float*)d_in[10];
    const float* gw5 = (const float*)d_in[11]; const float* gb5 = (const float*)d_in[12];
    const float* cw  = (const float*)d_in[13]; const float* cb  = (const float*)d_in[14];
    float* out = (float*)d_out;

    // Workspace layout (floats). Total 42,336,256 floats = 169.3 MB.
    float* W = (float*)d_ws;
    float* s1     = W + 0;            // 16,777,216  [8,32,256,256]   (reused as s3)
    float* s2     = W + 16777216;     //  8,388,608  [8,64,128,128]
    float* s4     = W + 25165824;     //  8,388,608  [8,256,64,64]
    float* scores = s2;               // 16,777,216  [4096,4096]  overlays s2+s4 (dead)
    float* attP   = W + 33554432;     //  8,388,608  [8][2][128][4096]
    float* gate   = W + 41943040;     //     32,768  [8][4096]
    float* invn   = W + 41975808;     //     32,768
    float* mq     = W + 42008576;     //     32,768
    float* invl   = W + 42041344;     //     32,768
    float* pm     = W + 42074112;     //    131,072  [32][4096] (per-batch reuse)
    float* pl     = W + 42205184;     //    131,072
    float* s3 = s1;

    // ---- gate conv stack ----
    conv1_k<<<dim3(4, 64, 64), 256, 0, stream>>>(imgs, masks, gw1, gb1, s1);
    conv_k<5, 2, 2><<<dim3(2, 32, 128), 256, 0, stream>>>(s1, gw2, gb2, s2, 32, 64, 256, 256, 128, 128);
    conv_k<5, 1, 2><<<dim3(2, 32, 256), 256, 0, stream>>>(s2, gw3, gb3, s3, 64, 128, 128, 128, 128, 128);
    conv_k<3, 2, 1><<<dim3(1, 16, 512), 256, 0, stream>>>(s3, gw4, gb4, s4, 128, 256, 128, 128, 64, 64);
    conv5_gate_k<<<dim3(16, 8), 256, 0, stream>>>(s4, gw5, gb5, gate);

    // ---- attention ----
    invn_k<<<dim3(16, 8), 256, 0, stream>>>(F, invn);
    for (int b = 0; b < 8; ++b) {
        scores_k<<<dim3(64, 64), 256, 0, stream>>>(F, invn, gate, scores, b);   // R1 fix: base ptr
        stats_part_k<<<dim3(16, 32), 256, 0, stream>>>(scores, pm, pl);
        stats_comb_k<<<dim3(16), 256, 0, stream>>>(pm, pl, mq + b * 4096, invl + b * 4096);
        attv_k<<<dim3(128, 2, 2), 256, 0, stream>>>(scores, F, mq + b * 4096, attP, b);
    }

    // ---- combiner ----
    combiner_k<<<dim3(16, 8, 8), 256, 0, stream>>>(attP, F, invl, cw, cb, out);
}

// Round 3
// 3871.299 us; speedup vs baseline: 1.2248x; 1.2248x over previous
//
#include <hip/hip_runtime.h>
#include <hip/hip_bf16.h>
#include <math.h>

// GatedAttention fp32 pipeline, R2: register-blocked direct convs.
// Shapes: B=8, C=128, H=W=64, P=4096; imgs [8,3,256,256], masks [8,1,256,256].
//
// R2: conv stack rewritten: each thread computes 4 output rows x 8 ocs at one ox.
// Per ic: load (3S+K) x K input patch to registers (40 loads for K=5/S=1), do
// 8*K*K*4 fma (800) -> 20:1 fma:load (was 4:1). Weights wave-uniform -> s_load.
// Summation order (ic,ky,kx) unchanged -> conv outputs bitwise identical to R1.

#define PI_F 3.1415926f

// ---------------- conv1: [8,4,256,256] -> [8,32,256,256], K7 S1 P3, relu --------------
__global__ __launch_bounds__(256) void conv1_reg_k(
    const float* __restrict__ imgs, const float* __restrict__ masks,
    const float* __restrict__ w, const float* __restrict__ bias,
    float* __restrict__ out)
{
    constexpr int K = 7, PAD = 3, NR = 10;     // 3*S+K, S=1
    const int lane = threadIdx.x & 63, wv = threadIdx.x >> 6;
    const int ox = blockIdx.x * 64 + lane;
    const int oy0 = blockIdx.y * 16 + wv * 4;
    const int ocg = blockIdx.z & 3, b = blockIdx.z >> 2;
    const int oc0 = ocg << 3;
    int ixo[K];
#pragma unroll
    for (int kx = 0; kx < K; ++kx) {
        int ix = ox + kx - PAD; if (ix < 0) ix = -ix; if (ix >= 256) ix = 510 - ix;
        ixo[kx] = ix;
    }
    int iyo[NR];
#pragma unroll
    for (int j = 0; j < NR; ++j) {
        int iy = oy0 + j - PAD; if (iy < 0) iy = -iy; if (iy >= 256) iy = 510 - iy;
        iyo[j] = iy << 8;
    }
    float acc[4][8];
#pragma unroll
    for (int oc = 0; oc < 8; ++oc) {
        float bv = bias[oc0 + oc];
#pragma unroll
        for (int r = 0; r < 4; ++r) acc[r][oc] = bv;
    }
    const int HW = 65536, KK = 49;
#pragma unroll
    for (int ic = 0; ic < 4; ++ic) {
        const float* p = (ic < 3) ? (imgs + (b * 3 + ic) * HW) : (masks + b * HW);
        float v[NR][K];
#pragma unroll
        for (int j = 0; j < NR; ++j)
#pragma unroll
            for (int kx = 0; kx < K; ++kx)
                v[j][kx] = p[iyo[j] + ixo[kx]];
#pragma unroll
        for (int oc = 0; oc < 8; ++oc) {
            const float* wc = w + ((oc0 + oc) * 4 + ic) * KK;
#pragma unroll
            for (int ky = 0; ky < K; ++ky)
#pragma unroll
                for (int kx = 0; kx < K; ++kx) {
                    float wt = wc[ky * K + kx];
#pragma unroll
                    for (int r = 0; r < 4; ++r)
                        acc[r][oc] = fmaf(wt, v[r + ky][kx], acc[r][oc]);
                }
        }
    }
    long ob = ((long)(b * 32 + oc0) << 16) + (oy0 << 8) + ox;
#pragma unroll
    for (int oc = 0; oc < 8; ++oc)
#pragma unroll
        for (int r = 0; r < 4; ++r)
            out[ob + ((long)oc << 16) + (r << 8)] = fmaxf(acc[r][oc], 0.f);
}

// -------- generic reflect conv, register-blocked: 4 rows x 8 oc per thread --------
template<int K, int S, int PAD>
__global__ __launch_bounds__(256) void conv_reg_k(
    const float* __restrict__ in, const float* __restrict__ w,
    const float* __restrict__ bias, float* __restrict__ out,
    int Cin, int Cout, int Hin, int Win, int Hout, int Wout)
{
    constexpr int NR = 3 * S + K;
    const int lane = threadIdx.x & 63, wv = threadIdx.x >> 6;
    const int ox = blockIdx.x * 64 + lane;
    const int oy0 = blockIdx.y * 16 + wv * 4;
    const int ng = Cout >> 3;
    const int ocg = blockIdx.z % ng, b = blockIdx.z / ng;
    const int oc0 = ocg << 3;
    int ixo[K];
#pragma unroll
    for (int kx = 0; kx < K; ++kx) {
        int ix = ox * S + kx - PAD; if (ix < 0) ix = -ix; if (ix >= Win) ix = 2 * Win - 2 - ix;
        ixo[kx] = ix;
    }
    int iyo[NR];
#pragma unroll
    for (int j = 0; j < NR; ++j) {
        int iy = oy0 * S + j - PAD; if (iy < 0) iy = -iy; if (iy >= Hin) iy = 2 * Hin - 2 - iy;
        iyo[j] = iy * Win;
    }
    float acc[4][8];
#pragma unroll
    for (int oc = 0; oc < 8; ++oc) {
        float bv = bias[oc0 + oc];
#pragma unroll
        for (int r = 0; r < 4; ++r) acc[r][oc] = bv;
    }
    const int HW = Hin * Win;
    constexpr int KK = K * K;
    const float* p = in + (long)b * Cin * HW;
    const float* wp = w + (long)oc0 * Cin * KK;
    for (int ic = 0; ic < Cin; ++ic) {
        float v[NR][K];
#pragma unroll
        for (int j = 0; j < NR; ++j)
#pragma unroll
            for (int kx = 0; kx < K; ++kx)
                v[j][kx] = p[iyo[j] + ixo[kx]];
#pragma unroll
        for (int oc = 0; oc < 8; ++oc) {
            const float* wc = wp + (long)oc * Cin * KK;
#pragma unroll
            for (int ky = 0; ky < K; ++ky)
#pragma unroll
                for (int kx = 0; kx < K; ++kx) {
                    float wt = wc[ky * K + kx];
#pragma unroll
                    for (int r = 0; r < 4; ++r)
                        acc[r][oc] = fmaf(wt, v[S * r + ky][kx], acc[r][oc]);
                }
        }
        p += HW;
        wp += KK;
    }
    const long oHW = (long)Hout * Wout;
    long ob = ((long)(b * Cout + oc0) * Hout + oy0) * Wout + ox;
#pragma unroll
    for (int oc = 0; oc < 8; ++oc)
#pragma unroll
        for (int r = 0; r < 4; ++r)
            out[ob + oc * oHW + r * Wout] = fmaxf(acc[r][oc], 0.f);
}

// ---------------- conv5 (256->1, K3 S1 P1) + relu + gate transform ----------------
__global__ __launch_bounds__(256) void conv5_gate_k(
    const float* __restrict__ s4, const float* __restrict__ w,
    const float* __restrict__ bias, float* __restrict__ gate)
{
    const int tid = threadIdx.x;
    const int p = blockIdx.x * 256 + tid;
    const int b = blockIdx.y;
    const int oy = p >> 6, ox = p & 63;
    int ixo[3], iyo[3];
#pragma unroll
    for (int k = 0; k < 3; ++k) {
        int ix = ox + k - 1; if (ix < 0) ix = -ix; if (ix >= 64) ix = 126 - ix;
        int iy = oy + k - 1; if (iy < 0) iy = -iy; if (iy >= 64) iy = 126 - iy;
        ixo[k] = ix; iyo[k] = iy << 6;
    }
    float acc = bias[0];
    const float* inb = s4 + (long)b * 256 * 4096;
    for (int ic = 0; ic < 256; ++ic) {
        const float* inc = inb + ic * 4096;
        const float* wc = w + ic * 9;
#pragma unroll
        for (int ky = 0; ky < 3; ++ky)
#pragma unroll
            for (int kx = 0; kx < 3; ++kx)
                acc = fmaf(wc[ky * 3 + kx], inc[iyo[ky] + ixo[kx]], acc);
    }
    float s = fmaxf(acc, 0.f);
    gate[(b << 12) + p] = tanf(PI_F * (tanhf(s) - 0.5f));
}

// ---------------- invn[b][p] = 1/sqrt(sum_c (F+1e-7)^2) ----------------
__global__ __launch_bounds__(256) void invn_k(const float* __restrict__ F, float* __restrict__ invn)
{
    const int p = blockIdx.x * 256 + threadIdx.x;
    const int b = blockIdx.y;
    const float* Fb = F + (long)b * 524288;
    float ss = 0.f;
#pragma unroll 8
    for (int c = 0; c < 128; ++c) {
        float v = Fb[c * 4096 + p] + 1e-7f;
        ss = fmaf(v, v, ss);
    }
    invn[(b << 12) + p] = 1.0f / sqrtf(ss);
}

// ---------------- scores[p][q] = invn[p]*sum_c (F[c,p]+eps)F[c,q] + gate[p] ----------
__global__ __launch_bounds__(256) void scores_k(
    const float* __restrict__ F, const float* __restrict__ invn,
    const float* __restrict__ gate, float* __restrict__ scores, int b)
{
    __shared__ float As[16][64];
    __shared__ float Bs[16][64];
    const int tid = threadIdx.x;
    const int tx = tid & 15, ty = tid >> 4;
    const int p0 = blockIdx.y << 6, q0 = blockIdx.x << 6;
    const float* Fb = F + (long)b * 524288;
    float acc[4][4] = {};
    const int lr = tid >> 4, lc = (tid & 15) << 2;
    for (int k0 = 0; k0 < 128; k0 += 16) {
        float4 av = *(const float4*)&Fb[(k0 + lr) * 4096 + p0 + lc];
        float4 bv = *(const float4*)&Fb[(k0 + lr) * 4096 + q0 + lc];
        av.x += 1e-7f; av.y += 1e-7f; av.z += 1e-7f; av.w += 1e-7f;
        *(float4*)&As[lr][lc] = av;
        *(float4*)&Bs[lr][lc] = bv;
        __syncthreads();
#pragma unroll
        for (int kk = 0; kk < 16; ++kk) {
            float4 a = *(const float4*)&As[kk][tx << 2];
            float4 bq = *(const float4*)&Bs[kk][ty << 2];
            acc[0][0] = fmaf(a.x, bq.x, acc[0][0]); acc[0][1] = fmaf(a.x, bq.y, acc[0][1]);
            acc[0][2] = fmaf(a.x, bq.z, acc[0][2]); acc[0][3] = fmaf(a.x, bq.w, acc[0][3]);
            acc[1][0] = fmaf(a.y, bq.x, acc[1][0]); acc[1][1] = fmaf(a.y, bq.y, acc[1][1]);
            acc[1][2] = fmaf(a.y, bq.z, acc[1][2]); acc[1][3] = fmaf(a.y, bq.w, acc[1][3]);
            acc[2][0] = fmaf(a.z, bq.x, acc[2][0]); acc[2][1] = fmaf(a.z, bq.y, acc[2][1]);
            acc[2][2] = fmaf(a.z, bq.z, acc[2][2]); acc[2][3] = fmaf(a.z, bq.w, acc[2][3]);
            acc[3][0] = fmaf(a.w, bq.x, acc[3][0]); acc[3][1] = fmaf(a.w, bq.y, acc[3][1]);
            acc[3][2] = fmaf(a.w, bq.z, acc[3][2]); acc[3][3] = fmaf(a.w, bq.w, acc[3][3]);
        }
        __syncthreads();
    }
    const int bp = b << 12;
#pragma unroll
    for (int i = 0; i < 4; ++i) {
        int p = p0 + (tx << 2) + i;
        float sc = invn[bp + p], g = gate[bp + p];
        float4 o;
        o.x = fmaf(acc[i][0], sc, g);
        o.y = fmaf(acc[i][1], sc, g);
        o.z = fmaf(acc[i][2], sc, g);
        o.w = fmaf(acc[i][3], sc, g);
        *(float4*)&scores[(long)p * 4096 + q0 + (ty << 2)] = o;
    }
}

// ---------------- softmax stats over p (columns of scores) ----------------
__global__ __launch_bounds__(256) void stats_part_k(
    const float* __restrict__ scores, float* __restrict__ pm, float* __restrict__ pl)
{
    const int q = blockIdx.x * 256 + threadIdx.x;
    const int pc = blockIdx.y;                 // 32 chunks x 128 rows
    float m = -3.4e38f, l = 0.f;
    const float* s = scores + (long)pc * 128 * 4096 + q;
    for (int r = 0; r < 128; ++r) {
        float x = s[(long)r * 4096];
        if (x > m) { l = l * __expf(m - x) + 1.f; m = x; }
        else l += __expf(x - m);
    }
    pm[pc * 4096 + q] = m;
    pl[pc * 4096 + q] = l;
}

__global__ __launch_bounds__(256) void stats_comb_k(
    const float* __restrict__ pm, const float* __restrict__ pl,
    float* __restrict__ mq, float* __restrict__ invl)
{
    const int q = blockIdx.x * 256 + threadIdx.x;
    float m = -3.4e38f;
#pragma unroll
    for (int i = 0; i < 32; ++i) m = fmaxf(m, pm[i * 4096 + q]);
    float l = 0.f;
#pragma unroll
    for (int i = 0; i < 32; ++i) l += pl[i * 4096 + q] * __expf(pm[i * 4096 + q] - m);
    mq[q] = m;
    invl[q] = 1.0f / l;
}

// ------- att partials: attP[ks][c][q] = sum_{p in ks-half} exp(s[p][q]-m[q])*(F[c,p]+eps)
__global__ __launch_bounds__(256) void attv_k(
    const float* __restrict__ scores, const float* __restrict__ F,
    const float* __restrict__ mq, float* __restrict__ attP, int b)
{
    __shared__ float Ks[32][64];   // [p][c]
    __shared__ float Es[32][32];   // [p][q], exp applied
    __shared__ float Ms[32];
    const int tid = threadIdx.x;
    const int tx = tid & 15, ty = tid >> 4;
    const int q0 = blockIdx.x << 5;          // 128 q-blocks
    const int c0 = blockIdx.y << 6;          // 2 c-halves
    const int ks = blockIdx.z;               // split-K = 2
    if (tid < 32) Ms[tid] = mq[q0 + tid];
    __syncthreads();
    const float* Fb = F + (long)b * 524288;
    float acc[4][2] = {};
    const int cc = tid >> 2, ps = (tid & 3) << 3;
    const int qq = tid & 31, pr = tid >> 5;
    const int pend = ks * 2048 + 2048;
    for (int p0 = ks * 2048; p0 < pend; p0 += 32) {
        float4 v0 = *(const float4*)&Fb[(long)(c0 + cc) * 4096 + p0 + ps];
        float4 v1 = *(const float4*)&Fb[(long)(c0 + cc) * 4096 + p0 + ps + 4];
        Ks[ps + 0][cc] = v0.x + 1e-7f;
        Ks[ps + 1][cc] = v0.y + 1e-7f;
        Ks[ps + 2][cc] = v0.z + 1e-7f;
        Ks[ps + 3][cc] = v0.w + 1e-7f;
        Ks[ps + 4][cc] = v1.x + 1e-7f;
        Ks[ps + 5][cc] = v1.y + 1e-7f;
        Ks[ps + 6][cc] = v1.z + 1e-7f;
        Ks[ps + 7][cc] = v1.w + 1e-7f;
        float m = Ms[qq];
#pragma unroll
        for (int i = 0; i < 4; ++i) {
            int pp = pr + (i << 3);
            Es[pp][qq] = __expf(scores[(long)(p0 + pp) * 4096 + q0 + qq] - m);
        }
        __syncthreads();
#pragma unroll
        for (int kk = 0; kk < 32; ++kk) {
            float4 a = *(const float4*)&Ks[kk][tx << 2];
            float2 e = *(const float2*)&Es[kk][ty << 1];
            acc[0][0] = fmaf(a.x, e.x, acc[0][0]); acc[0][1] = fmaf(a.x, e.y, acc[0][1]);
            acc[1][0] = fmaf(a.y, e.x, acc[1][0]); acc[1][1] = fmaf(a.y, e.y, acc[1][1]);
            acc[2][0] = fmaf(a.z, e.x, acc[2][0]); acc[2][1] = fmaf(a.z, e.y, acc[2][1]);
            acc[3][0] = fmaf(a.w, e.x, acc[3][0]); acc[3][1] = fmaf(a.w, e.y, acc[3][1]);
        }
        __syncthreads();
    }
    float* ap = attP + (long)(b * 2 + ks) * 128 * 4096;
#pragma unroll
    for (int i = 0; i < 4; ++i) {
        int c = c0 + (tx << 2) + i;
        int q = q0 + (ty << 1);
        ap[(long)c * 4096 + q]     = acc[i][0];
        ap[(long)c * 4096 + q + 1] = acc[i][1];
    }
}

// ---------------- combiner: out = cw[:, :128]*(att*invl) + cw[:, 128:]*F + cb --------
__global__ __launch_bounds__(256) void combiner_k(
    const float* __restrict__ attP, const float* __restrict__ F,
    const float* __restrict__ invl, const float* __restrict__ cw,
    const float* __restrict__ cb, float* __restrict__ out)
{
    const int tid = threadIdx.x;
    const int q = blockIdx.x * 256 + tid;
    const int o0 = blockIdx.y << 4;
    const int b = blockIdx.z;
    float il = invl[(b << 12) + q];
    const float* A0 = attP + (long)(b * 2 + 0) * 128 * 4096 + q;
    const float* A1 = attP + (long)(b * 2 + 1) * 128 * 4096 + q;
    const float* Fb = F + (long)b * 524288 + q;
    float acc[16];
#pragma unroll
    for (int j = 0; j < 16; ++j) acc[j] = cb[o0 + j];
    for (int c = 0; c < 128; ++c) {
        float a = (A0[(long)c * 4096] + A1[(long)c * 4096]) * il;
        float f = Fb[(long)c * 4096];
#pragma unroll
        for (int j = 0; j < 16; ++j) {
            acc[j] = fmaf(cw[(o0 + j) * 256 + c], a, acc[j]);
            acc[j] = fmaf(cw[(o0 + j) * 256 + 128 + c], f, acc[j]);
        }
    }
#pragma unroll
    for (int j = 0; j < 16; ++j)
        out[((long)(b * 128 + o0 + j) << 12) + q] = acc[j];
}

// =====================================================================================
extern "C" void kernel_launch(void* const* d_in, const int* in_sizes, int n_in,
                              void* d_out, int out_size, void* d_ws, size_t ws_size,
                              hipStream_t stream)
{
    const float* F     = (const float*)d_in[0];   // feature_in [8,128,64,64]
    const float* imgs  = (const float*)d_in[1];   // [8,3,256,256]
    const float* masks = (const float*)d_in[2];   // [8,1,256,256]
    const float* gw1 = (const float*)d_in[3];  const float* gb1 = (const float*)d_in[4];
    const float* gw2 = (const float*)d_in[5];  const float* gb2 = (const float*)d_in[6];
    const float* gw3 = (const float*)d_in[7];  const float* gb3 = (const float*)d_in[8];
    const float* gw4 = (const float*)d_in[9];  const float* gb4 = (const float*)d_in[10];
    const float* gw5 = (const float*)d_in[11]; const float* gb5 = (const float*)d_in[12];
    const float* cw  = (const float*)d_in[13]; const float* cb  = (const float*)d_in[14];
    float* out = (float*)d_out;

    // Workspace layout (floats). Total 42,336,256 floats = 169.3 MB.
    float* W = (float*)d_ws;
    float* s1     = W + 0;            // 16,777,216  [8,32,256,256]   (reused as s3)
    float* s2     = W + 16777216;     //  8,388,608  [8,64,128,128]
    float* s4     = W + 25165824;     //  8,388,608  [8,256,64,64]
    float* scores = s2;               // 16,777,216  [4096,4096]  overlays s2+s4 (dead)
    float* attP   = W + 33554432;     //  8,388,608  [8][2][128][4096]
    float* gate   = W + 41943040;     //     32,768  [8][4096]
    float* invn   = W + 41975808;     //     32,768
    float* mq     = W + 42008576;     //     32,768
    float* invl   = W + 42041344;     //     32,768
    float* pm     = W + 42074112;     //    131,072  [32][4096] (per-batch reuse)
    float* pl     = W + 42205184;     //    131,072
    float* s3 = s1;

    // ---- gate conv stack (register-blocked) ----
    conv1_reg_k<<<dim3(4, 16, 32), 256, 0, stream>>>(imgs, masks, gw1, gb1, s1);
    conv_reg_k<5, 2, 2><<<dim3(2, 8, 64), 256, 0, stream>>>(s1, gw2, gb2, s2, 32, 64, 256, 256, 128, 128);
    conv_reg_k<5, 1, 2><<<dim3(2, 8, 128), 256, 0, stream>>>(s2, gw3, gb3, s3, 64, 128, 128, 128, 128, 128);
    conv_reg_k<3, 2, 1><<<dim3(1, 4, 256), 256, 0, stream>>>(s3, gw4, gb4, s4, 128, 256, 128, 128, 64, 64);
    conv5_gate_k<<<dim3(16, 8), 256, 0, stream>>>(s4, gw5, gb5, gate);

    // ---- attention ----
    invn_k<<<dim3(16, 8), 256, 0, stream>>>(F, invn);
    for (int b = 0; b < 8; ++b) {
        scores_k<<<dim3(64, 64), 256, 0, stream>>>(F, invn, gate, scores, b);
        stats_part_k<<<dim3(16, 32), 256, 0, stream>>>(scores, pm, pl);
        stats_comb_k<<<dim3(16), 256, 0, stream>>>(pm, pl, mq + b * 4096, invl + b * 4096);
        attv_k<<<dim3(128, 2, 2), 256, 0, stream>>>(scores, F, mq + b * 4096, attP, b);
    }

    // ---- combiner ----
    combiner_k<<<dim3(16, 8, 8), 256, 0, stream>>>(attP, F, invl, cw, cb, out);
}

// Round 4
// 3164.219 us; speedup vs baseline: 1.4985x; 1.2235x over previous
//
#include <hip/hip_runtime.h>
#include <hip/hip_bf16.h>
#include <math.h>

// GatedAttention R4: row-streaming fp32 convs (no spills) + bf16-MFMA attention.
// B=8, C=128, H=W=64, P=4096.
// Numerics: conv stack + gate stay fp32 (dgate/ds up to ~8800 -> bf16 conv noise
// would blow the 0.032 threshold). Attention GEMMs bf16 (score err ~6e-3 -> ~0.6%
// softmax weight error -> out err ~5e-3). gate/invn applied in fp32 epilogue.

#define PI_F 3.1415926f

typedef __attribute__((ext_vector_type(8))) short short8;
typedef __attribute__((ext_vector_type(4))) float f32x4;
typedef unsigned short ushort_t;

__device__ __forceinline__ ushort_t f2bf(float x) {
    unsigned u = __float_as_uint(x);
    unsigned r = (u + 0x7FFFu + ((u >> 16) & 1u)) >> 16;
    return (ushort_t)r;
}

// ---------------- conv1: [8,4,256,256] -> [8,32,256,256], K7 S1 P3, relu ------------
__global__ __launch_bounds__(256) void conv1_row_k(
    const float* __restrict__ imgs, const float* __restrict__ masks,
    const float* __restrict__ w, const float* __restrict__ bias,
    float* __restrict__ out)
{
    constexpr int K = 7, PAD = 3, NR = 10;
    const int lane = threadIdx.x & 63, wv = threadIdx.x >> 6;
    const int ox = blockIdx.x * 64 + lane;
    const int oy0 = blockIdx.y * 16 + wv * 4;
    const int ocg = blockIdx.z & 3, b = blockIdx.z >> 2;
    const int oc0 = ocg << 3;
    int ixo[K];
#pragma unroll
    for (int kx = 0; kx < K; ++kx) {
        int ix = ox + kx - PAD; if (ix < 0) ix = -ix; if (ix >= 256) ix = 510 - ix;
        ixo[kx] = ix;
    }
    int iyo[NR];
#pragma unroll
    for (int j = 0; j < NR; ++j) {
        int iy = oy0 + j - PAD; if (iy < 0) iy = -iy; if (iy >= 256) iy = 510 - iy;
        iyo[j] = iy << 8;
    }
    float acc[4][8];
#pragma unroll
    for (int oc = 0; oc < 8; ++oc) {
        float bv = bias[oc0 + oc];
#pragma unroll
        for (int r = 0; r < 4; ++r) acc[r][oc] = bv;
    }
    const int HW = 65536;
#pragma unroll
    for (int ic = 0; ic < 4; ++ic) {
        const float* p = (ic < 3) ? (imgs + (b * 3 + ic) * HW) : (masks + b * HW);
#pragma unroll
        for (int j = 0; j < NR; ++j) {
            float row[K];
#pragma unroll
            for (int kx = 0; kx < K; ++kx) row[kx] = p[iyo[j] + ixo[kx]];
#pragma unroll
            for (int r = 0; r < 4; ++r) {
                const int ky = j - r;
                if (ky >= 0 && ky < K) {
#pragma unroll
                    for (int oc = 0; oc < 8; ++oc) {
                        const float* wc = w + ((oc0 + oc) * 4 + ic) * 49 + ky * K;
#pragma unroll
                        for (int kx = 0; kx < K; ++kx)
                            acc[r][oc] = fmaf(wc[kx], row[kx], acc[r][oc]);
                    }
                }
            }
        }
    }
    long ob = ((long)(b * 32 + oc0) << 16) + (oy0 << 8) + ox;
#pragma unroll
    for (int oc = 0; oc < 8; ++oc)
#pragma unroll
        for (int r = 0; r < 4; ++r)
            out[ob + ((long)oc << 16) + (r << 8)] = fmaxf(acc[r][oc], 0.f);
}

// -------- generic reflect conv, row-streaming: 4 rows x 8 oc per thread -----------
template<int K, int S, int PAD>
__global__ __launch_bounds__(256) void conv_row_k(
    const float* __restrict__ in, const float* __restrict__ w,
    const float* __restrict__ bias, float* __restrict__ out,
    int Cin, int Cout, int Hin, int Win, int Hout, int Wout)
{
    constexpr int NR = 3 * S + K;
    constexpr int KK = K * K;
    const int lane = threadIdx.x & 63, wv = threadIdx.x >> 6;
    const int ox = blockIdx.x * 64 + lane;
    const int oy0 = blockIdx.y * 16 + wv * 4;
    const int ng = Cout >> 3;
    const int ocg = blockIdx.z % ng, b = blockIdx.z / ng;
    const int oc0 = ocg << 3;
    int ixo[K];
#pragma unroll
    for (int kx = 0; kx < K; ++kx) {
        int ix = ox * S + kx - PAD; if (ix < 0) ix = -ix; if (ix >= Win) ix = 2 * Win - 2 - ix;
        ixo[kx] = ix;
    }
    int iyo[NR];
#pragma unroll
    for (int j = 0; j < NR; ++j) {
        int iy = oy0 * S + j - PAD; if (iy < 0) iy = -iy; if (iy >= Hin) iy = 2 * Hin - 2 - iy;
        iyo[j] = iy * Win;
    }
    float acc[4][8];
#pragma unroll
    for (int oc = 0; oc < 8; ++oc) {
        float bv = bias[oc0 + oc];
#pragma unroll
        for (int r = 0; r < 4; ++r) acc[r][oc] = bv;
    }
    const int HW = Hin * Win;
    const float* p = in + (long)b * Cin * HW;
    const float* wp = w + (long)oc0 * Cin * KK;
    for (int ic = 0; ic < Cin; ++ic) {
#pragma unroll
        for (int j = 0; j < NR; ++j) {
            float row[K];
#pragma unroll
            for (int kx = 0; kx < K; ++kx) row[kx] = p[iyo[j] + ixo[kx]];
#pragma unroll
            for (int r = 0; r < 4; ++r) {
                const int ky = j - S * r;
                if (ky >= 0 && ky < K) {
#pragma unroll
                    for (int oc = 0; oc < 8; ++oc) {
                        const float* wc = wp + ((long)oc * Cin + ic) * KK + ky * K;
#pragma unroll
                        for (int kx = 0; kx < K; ++kx)
                            acc[r][oc] = fmaf(wc[kx], row[kx], acc[r][oc]);
                    }
                }
            }
        }
        p += HW;
    }
    const long oHW = (long)Hout * Wout;
    long ob = ((long)(b * Cout + oc0) * Hout + oy0) * Wout + ox;
#pragma unroll
    for (int oc = 0; oc < 8; ++oc)
#pragma unroll
        for (int r = 0; r < 4; ++r)
            out[ob + oc * oHW + r * Wout] = fmaxf(acc[r][oc], 0.f);
}

// -------- conv5 (256->1, K3 S1 P1) + relu + gate, ic-parallel (4 groups) ----------
__global__ __launch_bounds__(256) void conv5_gate_k(
    const float* __restrict__ s4, const float* __restrict__ w,
    const float* __restrict__ bias, float* __restrict__ gate)
{
    const int tid = threadIdx.x;
    const int lane = tid & 63, g = tid >> 6;
    const int oy = blockIdx.x, b = blockIdx.y;
    int ixo[3], iyo[3];
#pragma unroll
    for (int k = 0; k < 3; ++k) {
        int ix = lane + k - 1; if (ix < 0) ix = -ix; if (ix >= 64) ix = 126 - ix;
        int iy = oy + k - 1; if (iy < 0) iy = -iy; if (iy >= 64) iy = 126 - iy;
        ixo[k] = ix; iyo[k] = iy << 6;
    }
    float part = 0.f;
    const float* inb = s4 + ((long)b * 256 + g * 64) * 4096;
    const float* wg = w + g * 64 * 9;
    for (int ic = 0; ic < 64; ++ic) {
        const float* inc = inb + ic * 4096;
        const float* wc = wg + ic * 9;
#pragma unroll
        for (int ky = 0; ky < 3; ++ky)
#pragma unroll
            for (int kx = 0; kx < 3; ++kx)
                part = fmaf(wc[ky * 3 + kx], inc[iyo[ky] + ixo[kx]], part);
    }
    __shared__ float red[4][64];
    red[g][lane] = part;
    __syncthreads();
    if (tid < 64) {
        float s = bias[0] + red[0][tid] + red[1][tid] + red[2][tid] + red[3][tid];
        s = fmaxf(s, 0.f);
        gate[(b << 12) + (oy << 6) + tid] = tanf(PI_F * (tanhf(s) - 0.5f));
    }
}

// ---------------- invn[b][p] = 1/sqrt(sum_c (F+1e-7)^2) ----------------
__global__ __launch_bounds__(256) void invn_k(const float* __restrict__ F, float* __restrict__ invn)
{
    const int p = blockIdx.x * 256 + threadIdx.x;
    const int b = blockIdx.y;
    const float* Fb = F + (long)b * 524288;
    float ss = 0.f;
#pragma unroll 8
    for (int c = 0; c < 128; ++c) {
        float v = Fb[c * 4096 + p] + 1e-7f;
        ss = fmaf(v, v, ss);
    }
    invn[(b << 12) + p] = 1.0f / sqrtf(ss);
}

// -------- prep: Fo16[b][c][p] = bf16(F), Ft16[b][p][c] = bf16(F^T) ---------------
__global__ __launch_bounds__(256) void prep_bf16_k(
    const float* __restrict__ F, ushort_t* __restrict__ Fo16, ushort_t* __restrict__ Ft16)
{
    __shared__ float Ls[128][65];
    const int tid = threadIdx.x;
    const int lane = tid & 63, wv = tid >> 6;
    const int p0 = blockIdx.x * 64, b = blockIdx.y;
#pragma unroll 8
    for (int cc = 0; cc < 32; ++cc) {
        int c = wv * 32 + cc;
        long idx = ((long)b * 128 + c) * 4096 + p0 + lane;
        float v = F[idx];
        Fo16[idx] = f2bf(v);
        Ls[c][lane] = v;
    }
    __syncthreads();
#pragma unroll 8
    for (int i = 0; i < 32; ++i) {
        int flat = tid + 256 * i;
        int c = flat & 127, pl_ = flat >> 7;
        Ft16[((long)b * 4096 + p0 + pl_) * 128 + c] = f2bf(Ls[c][pl_]);
    }
}

// -------- scores MFMA: 128x128 tile; epilogue fuses invn/gate + softmax stats -----
__global__ __launch_bounds__(256) void scores_mfma_k(
    const ushort_t* __restrict__ Ft16, const float* __restrict__ invn,
    const float* __restrict__ gate, float* __restrict__ scores,
    float* __restrict__ pm, float* __restrict__ pl, int b)
{
    const int tid = threadIdx.x;
    const int lane = tid & 63, wid = tid >> 6;
    const int wm = wid & 1, wn = wid >> 1;
    const int l15 = lane & 15, quad = lane >> 4;
    const int qb = blockIdx.x, pb = blockIdx.y;
    const int p_base = pb * 128 + wm * 64;
    const int q_base = qb * 128 + wn * 64;
    const ushort_t* Fb = Ft16 + (long)b * 4096 * 128;

    f32x4 acc[4][4];
#pragma unroll
    for (int mi = 0; mi < 4; ++mi)
#pragma unroll
        for (int ni = 0; ni < 4; ++ni) acc[mi][ni] = (f32x4){0.f, 0.f, 0.f, 0.f};

#pragma unroll
    for (int c0 = 0; c0 < 128; c0 += 32) {
        short8 A[4], B[4];
#pragma unroll
        for (int mi = 0; mi < 4; ++mi)
            A[mi] = *(const short8*)(Fb + (long)(p_base + mi * 16 + l15) * 128 + c0 + quad * 8);
#pragma unroll
        for (int ni = 0; ni < 4; ++ni)
            B[ni] = *(const short8*)(Fb + (long)(q_base + ni * 16 + l15) * 128 + c0 + quad * 8);
#pragma unroll
        for (int mi = 0; mi < 4; ++mi)
#pragma unroll
            for (int ni = 0; ni < 4; ++ni)
                acc[mi][ni] = __builtin_amdgcn_mfma_f32_16x16x32_bf16(A[mi], B[ni], acc[mi][ni], 0, 0, 0);
    }

    // epilogue: s = acc*invn[p] + gate[p]; store; per-column (q) m/l over this block's 128 p
    const int bp = b << 12;
    float iv[4][4], gt[4][4];
#pragma unroll
    for (int mi = 0; mi < 4; ++mi)
#pragma unroll
        for (int r = 0; r < 4; ++r) {
            int p = p_base + mi * 16 + quad * 4 + r;
            iv[mi][r] = invn[bp + p];
            gt[mi][r] = gate[bp + p];
        }

    __shared__ float Rm[2][2][64], Rl[2][2][64];
#pragma unroll
    for (int ni = 0; ni < 4; ++ni) {
        const int q = q_base + ni * 16 + l15;
        float mloc = -3.4e38f;
#pragma unroll
        for (int mi = 0; mi < 4; ++mi)
#pragma unroll
            for (int r = 0; r < 4; ++r) {
                float s = fmaf(acc[mi][ni][r], iv[mi][r], gt[mi][r]);
                acc[mi][ni][r] = s;
                mloc = fmaxf(mloc, s);
                int p = p_base + mi * 16 + quad * 4 + r;
                scores[(long)p * 4096 + q] = s;
            }
        // column max across quads (lanes q, q+16, q+32, q+48)
        mloc = fmaxf(mloc, __shfl_xor(mloc, 16));
        mloc = fmaxf(mloc, __shfl_xor(mloc, 32));
        float lloc = 0.f;
#pragma unroll
        for (int mi = 0; mi < 4; ++mi)
#pragma unroll
            for (int r = 0; r < 4; ++r)
                lloc += __expf(acc[mi][ni][r] - mloc);
        lloc += __shfl_xor(lloc, 16);
        lloc += __shfl_xor(lloc, 32);
        if (quad == 0) {
            Rm[wn][wm][ni * 16 + l15] = mloc;
            Rl[wn][wm][ni * 16 + l15] = lloc;
        }
    }
    __syncthreads();
    if (tid < 128) {
        int wn2 = tid >> 6, qq = tid & 63;
        float ma = Rm[wn2][0][qq], mb2 = Rm[wn2][1][qq];
        float M = fmaxf(ma, mb2);
        float L = Rl[wn2][0][qq] * __expf(ma - M) + Rl[wn2][1][qq] * __expf(mb2 - M);
        pm[pb * 4096 + blockIdx.x * 128 + tid] = M;
        pl[pb * 4096 + blockIdx.x * 128 + tid] = L;
    }
}

// -------- attv MFMA: attP[ks][c][q] = sum_{p in ks slice} exp(s[p][q]-m[q]) * F[c][p]
__global__ __launch_bounds__(256) void attv_mfma_k(
    const float* __restrict__ scores, const ushort_t* __restrict__ Fo16,
    const float* __restrict__ pm, const float* __restrict__ pl,
    float* __restrict__ invl, float* __restrict__ attP, int b)
{
    __shared__ ushort_t Es[64][72];
    __shared__ float Ms[64];
    const int tid = threadIdx.x;
    const int lane = tid & 63, wid = tid >> 6;
    const int wm = wid & 1, wn = wid >> 1;
    const int l15 = lane & 15, quad = lane >> 4;
    const int qb = blockIdx.x, ks = blockIdx.y;
    const int q_base = qb * 64;
    const int m0 = wm * 64, n0 = wn * 32;

    // fused stats-combine: m[q], and invl (ks==0 writes)
    if (tid < 64) {
        int q = q_base + tid;
        float m = -3.4e38f;
#pragma unroll 8
        for (int i = 0; i < 32; ++i) m = fmaxf(m, pm[i * 4096 + q]);
        float l = 0.f;
#pragma unroll 8
        for (int i = 0; i < 32; ++i) l += pl[i * 4096 + q] * __expf(pm[i * 4096 + q] - m);
        Ms[tid] = m;
        if (ks == 0) invl[(b << 12) + q] = 1.0f / l;
    }
    __syncthreads();

    const ushort_t* Fob = Fo16 + (long)b * 128 * 4096;
    f32x4 acc[4][2];
#pragma unroll
    for (int mi = 0; mi < 4; ++mi)
#pragma unroll
        for (int ni = 0; ni < 2; ++ni) acc[mi][ni] = (f32x4){0.f, 0.f, 0.f, 0.f};

    const int p_start = ks * 512;
    for (int pc = p_start; pc < p_start + 512; pc += 64) {
        // stage exp tile: Es[q 64][p 64] bf16
#pragma unroll
        for (int i = 0; i < 4; ++i) {
            int idx = tid + 256 * i;                 // float4 id, 1024 total
            int p_l = idx >> 4, qv = (idx & 15) << 2;
            float4 sv = *(const float4*)&scores[(long)(pc + p_l) * 4096 + q_base + qv];
            Es[qv + 0][p_l] = f2bf(__expf(sv.x - Ms[qv + 0]));
            Es[qv + 1][p_l] = f2bf(__expf(sv.y - Ms[qv + 1]));
            Es[qv + 2][p_l] = f2bf(__expf(sv.z - Ms[qv + 2]));
            Es[qv + 3][p_l] = f2bf(__expf(sv.w - Ms[qv + 3]));
        }
        __syncthreads();
#pragma unroll
        for (int ksub = 0; ksub < 2; ++ksub) {
            const int pk = pc + ksub * 32 + quad * 8;
            short8 A[4], B[2];
#pragma unroll
            for (int mi = 0; mi < 4; ++mi)
                A[mi] = *(const short8*)(Fob + (long)(m0 + mi * 16 + l15) * 4096 + pk);
#pragma unroll
            for (int ni = 0; ni < 2; ++ni)
                B[ni] = *(const short8*)&Es[n0 + ni * 16 + l15][ksub * 32 + quad * 8];
#pragma unroll
            for (int mi = 0; mi < 4; ++mi)
#pragma unroll
                for (int ni = 0; ni < 2; ++ni)
                    acc[mi][ni] = __builtin_amdgcn_mfma_f32_16x16x32_bf16(A[mi], B[ni], acc[mi][ni], 0, 0, 0);
        }
        __syncthreads();
    }
#pragma unroll
    for (int mi = 0; mi < 4; ++mi)
#pragma unroll
        for (int ni = 0; ni < 2; ++ni)
#pragma unroll
            for (int r = 0; r < 4; ++r) {
                int c = m0 + mi * 16 + quad * 4 + r;
                int q = q_base + n0 + ni * 16 + l15;
                attP[(long)(ks * 128 + c) * 4096 + q] = acc[mi][ni][r];
            }
}

// ---------------- combiner (per batch): out = cw[:, :128]*(att*invl) + cw[:, 128:]*F + cb
__global__ __launch_bounds__(256) void combiner_k(
    const float* __restrict__ attP, const float* __restrict__ F,
    const float* __restrict__ invl, const float* __restrict__ cw,
    const float* __restrict__ cb, float* __restrict__ out, int b)
{
    const int tid = threadIdx.x;
    const int q = blockIdx.x * 256 + tid;
    const int o0 = blockIdx.y << 4;
    float il = invl[(b << 12) + q];
    const float* Fb = F + (long)b * 524288 + q;
    float acc[16];
#pragma unroll
    for (int j = 0; j < 16; ++j) acc[j] = cb[o0 + j];
    for (int c = 0; c < 128; ++c) {
        float a = 0.f;
#pragma unroll
        for (int ks = 0; ks < 8; ++ks)
            a += attP[(long)(ks * 128 + c) * 4096 + q];
        a *= il;
        float f = Fb[(long)c * 4096];
#pragma unroll
        for (int j = 0; j < 16; ++j) {
            acc[j] = fmaf(cw[(o0 + j) * 256 + c], a, acc[j]);
            acc[j] = fmaf(cw[(o0 + j) * 256 + 128 + c], f, acc[j]);
        }
    }
#pragma unroll
    for (int j = 0; j < 16; ++j)
        out[((long)(b * 128 + o0 + j) << 12) + q] = acc[j];
}

// =====================================================================================
extern "C" void kernel_launch(void* const* d_in, const int* in_sizes, int n_in,
                              void* d_out, int out_size, void* d_ws, size_t ws_size,
                              hipStream_t stream)
{
    const float* F     = (const float*)d_in[0];
    const float* imgs  = (const float*)d_in[1];
    const float* masks = (const float*)d_in[2];
    const float* gw1 = (const float*)d_in[3];  const float* gb1 = (const float*)d_in[4];
    const float* gw2 = (const float*)d_in[5];  const float* gb2 = (const float*)d_in[6];
    const float* gw3 = (const float*)d_in[7];  const float* gb3 = (const float*)d_in[8];
    const float* gw4 = (const float*)d_in[9];  const float* gb4 = (const float*)d_in[10];
    const float* gw5 = (const float*)d_in[11]; const float* gb5 = (const float*)d_in[12];
    const float* cw  = (const float*)d_in[13]; const float* cb  = (const float*)d_in[14];
    float* out = (float*)d_out;

    // Workspace layout (float offsets). Total 42,303,488 floats = 169.2 MB.
    float* W = (float*)d_ws;
    float*    s1     = W + 0;            // [8,32,256,256] (16.78M)
    float*    s2     = W + 16777216;     // [8,64,128,128] (8.39M)
    float*    s4     = W + 25165824;     // [8,256,64,64]  (8.39M)
    float*    scores = W + 16777216;     // [4096,4096] overlays s2+s4 (dead by then)
    float*    attP   = W + 33554432;     // [8][128][4096] (4.19M)
    ushort_t* Fo16   = (ushort_t*)(W + 37748736);  // [8][128][4096] bf16
    ushort_t* Ft16   = (ushort_t*)(W + 39845888);  // [8][4096][128] bf16
    float*    gate   = W + 41943040;     // [8][4096]
    float*    invn   = W + 41975808;
    float*    invl   = W + 42008576;
    float*    pm     = W + 42041344;     // [32][4096]
    float*    pl     = W + 42172416;     // [32][4096]
    float*    s3 = s1;

    // ---- gate conv stack (row-streaming fp32) ----
    conv1_row_k<<<dim3(4, 16, 32), 256, 0, stream>>>(imgs, masks, gw1, gb1, s1);
    conv_row_k<5, 2, 2><<<dim3(2, 8, 64), 256, 0, stream>>>(s1, gw2, gb2, s2, 32, 64, 256, 256, 128, 128);
    conv_row_k<5, 1, 2><<<dim3(2, 8, 128), 256, 0, stream>>>(s2, gw3, gb3, s3, 64, 128, 128, 128, 128, 128);
    conv_row_k<3, 2, 1><<<dim3(1, 4, 256), 256, 0, stream>>>(s3, gw4, gb4, s4, 128, 256, 128, 128, 64, 64);
    conv5_gate_k<<<dim3(64, 8), 256, 0, stream>>>(s4, gw5, gb5, gate);

    // ---- attention prep ----
    invn_k<<<dim3(16, 8), 256, 0, stream>>>(F, invn);
    prep_bf16_k<<<dim3(64, 8), 256, 0, stream>>>(F, Fo16, Ft16);

    // ---- per-batch attention (MFMA) ----
    for (int b = 0; b < 8; ++b) {
        scores_mfma_k<<<dim3(32, 32), 256, 0, stream>>>(Ft16, invn, gate, scores, pm, pl, b);
        attv_mfma_k<<<dim3(64, 8), 256, 0, stream>>>(scores, Fo16, pm, pl, invl, attP, b);
        combiner_k<<<dim3(16, 8), 256, 0, stream>>>(attP, F, invl, cw, cb, out, b);
    }
}

// Round 6
// 1962.682 us; speedup vs baseline: 2.4158x; 1.6122x over previous
//
#include <hip/hip_runtime.h>
#include <hip/hip_bf16.h>
#include <hip/hip_fp16.h>
#include <math.h>

// GatedAttention R6 (= R5 + compile fix): conv2/3/4 -> split-fp16 (hi+lo) MFMA GEMMs,
// fp32-equivalent precision (dropped lo*lo term ~2^-22 rel). Inputs kept channel-last
// reflect-padded fp16 hi/lo planes; conv1 epilogue writes that layout directly.
// Attention = R4 (bf16 MFMA, passed at absmax 0.0078).

#define PI_F 3.1415926f

typedef __attribute__((ext_vector_type(8))) short short8;
typedef __attribute__((ext_vector_type(4))) float f32x4;
typedef _Float16 half8 __attribute__((ext_vector_type(8)));
typedef __attribute__((ext_vector_type(4))) unsigned short u16x4;
typedef __attribute__((ext_vector_type(8))) unsigned short u16x8;
typedef unsigned short ushort_t;

__device__ __forceinline__ ushort_t f2bf(float x) {
    unsigned u = __float_as_uint(x);
    unsigned r = (u + 0x7FFFu + ((u >> 16) & 1u)) >> 16;
    return (ushort_t)r;
}
__device__ __forceinline__ void split16(float x, ushort_t& h, ushort_t& l) {
    __half hh = __float2half(x);
    h = __half_as_ushort(hh);
    l = __half_as_ushort(__float2half(x - __half2float(hh)));
}

// ---------------- weight transform: OIHW fp32 -> [ky*kx][oc][ic] fp16 hi/lo --------
__global__ __launch_bounds__(256) void transform_w_k(
    const float* __restrict__ w, ushort_t* __restrict__ Wh, ushort_t* __restrict__ Wl,
    int Cout, int Cin, int KK)
{
    int idx = blockIdx.x * 256 + threadIdx.x;
    int N = Cout * Cin * KK;
    if (idx >= N) return;
    int oc = idx / (Cin * KK);
    int rem = idx - oc * Cin * KK;
    int ic = rem / KK;
    int t = rem - ic * KK;
    float v = w[idx];
    long dst = ((long)t * Cout + oc) * Cin + ic;
    split16(v, Wh[dst], Wl[dst]);
}

// ------- pad-fill for channel-last reflect-padded buffers (border from interior) ----
__global__ __launch_bounds__(256) void pad_cl_k(
    ushort_t* __restrict__ Xh, ushort_t* __restrict__ Xl,
    int Hp, int Wp, int PAD, int C, int H, int W)
{
    const int iy = blockIdx.x, b = blockIdx.y;
    int t = iy - PAD; if (t < 0) t = -t; if (t >= H) t = 2 * H - 2 - t;
    const int iys = t + PAD;
    const long rowd = ((long)(b * Hp + iy) * Wp) * C;
    const long rows = ((long)(b * Hp + iys) * Wp) * C;
    const int nch = Wp * (C >> 3);
    for (int idx = threadIdx.x; idx < nch; idx += 256) {
        int x = idx / (C >> 3);
        int cg = (idx - x * (C >> 3)) << 3;
        int t2 = x - PAD; if (t2 < 0) t2 = -t2; if (t2 >= W) t2 = 2 * W - 2 - t2;
        int xs = t2 + PAD;
        if (xs == x && iys == iy) continue;
        *(int4*)&Xh[rowd + (long)x * C + cg] = *(const int4*)&Xh[rows + (long)xs * C + cg];
        *(int4*)&Xl[rowd + (long)x * C + cg] = *(const int4*)&Xl[rows + (long)xs * C + cg];
    }
}

// ---------------- conv1 (VALU, K7 S1 P3) -> channel-last fp16 h/l into Xcl2 ---------
__global__ __launch_bounds__(256) void conv1_row_k(
    const float* __restrict__ imgs, const float* __restrict__ masks,
    const float* __restrict__ w, const float* __restrict__ bias,
    ushort_t* __restrict__ Oh, ushort_t* __restrict__ Ol)
{
    constexpr int K = 7, PAD = 3, NR = 10;
    const int lane = threadIdx.x & 63, wv = threadIdx.x >> 6;
    const int ox = blockIdx.x * 64 + lane;
    const int oy0 = blockIdx.y * 16 + wv * 4;
    const int ocg = blockIdx.z & 3, b = blockIdx.z >> 2;
    const int oc0 = ocg << 3;
    int ixo[K];
#pragma unroll
    for (int kx = 0; kx < K; ++kx) {
        int ix = ox + kx - PAD; if (ix < 0) ix = -ix; if (ix >= 256) ix = 510 - ix;
        ixo[kx] = ix;
    }
    int iyo[NR];
#pragma unroll
    for (int j = 0; j < NR; ++j) {
        int iy = oy0 + j - PAD; if (iy < 0) iy = -iy; if (iy >= 256) iy = 510 - iy;
        iyo[j] = iy << 8;
    }
    float acc[4][8];
#pragma unroll
    for (int oc = 0; oc < 8; ++oc) {
        float bv = bias[oc0 + oc];
#pragma unroll
        for (int r = 0; r < 4; ++r) acc[r][oc] = bv;
    }
    const int HW = 65536;
#pragma unroll
    for (int ic = 0; ic < 4; ++ic) {
        const float* p = (ic < 3) ? (imgs + (b * 3 + ic) * HW) : (masks + b * HW);
#pragma unroll
        for (int j = 0; j < NR; ++j) {
            float row[K];
#pragma unroll
            for (int kx = 0; kx < K; ++kx) row[kx] = p[iyo[j] + ixo[kx]];
#pragma unroll
            for (int r = 0; r < 4; ++r) {
                const int ky = j - r;
                if (ky >= 0 && ky < K) {
#pragma unroll
                    for (int oc = 0; oc < 8; ++oc) {
                        const float* wc = w + ((oc0 + oc) * 4 + ic) * 49 + ky * K;
#pragma unroll
                        for (int kx = 0; kx < K; ++kx)
                            acc[r][oc] = fmaf(wc[kx], row[kx], acc[r][oc]);
                    }
                }
            }
        }
    }
    // write channel-last padded (pad=2 for conv2): Xcl2[b][oy+2][ox+2][oc]
#pragma unroll
    for (int r = 0; r < 4; ++r) {
        long o = ((long)(b * 260 + oy0 + r + 2) * 260 + ox + 2) * 32 + oc0;
        u16x8 hv, lv;
#pragma unroll
        for (int oc = 0; oc < 8; ++oc) {
            float v = fmaxf(acc[r][oc], 0.f);
            ushort_t h, l;
            split16(v, h, l);
            hv[oc] = h; lv[oc] = l;
        }
        *(u16x8*)&Oh[o] = hv;
        *(u16x8*)&Ol[o] = lv;
    }
}

// ---------------- generic MFMA conv (split-fp16), tile MT oc x 64 px ----------------
template<int K, int S, int CIN, int CSTG, int MT, bool WRITE_CL>
__global__ __launch_bounds__(256) void conv_mfma_k(
    const ushort_t* __restrict__ Xh, const ushort_t* __restrict__ Xl,
    const ushort_t* __restrict__ Wh, const ushort_t* __restrict__ Wl,
    const float* __restrict__ bias,
    int Hp, int Wp, int CoutT,
    ushort_t* __restrict__ Oh, ushort_t* __restrict__ Ol, int Hpn, int Wpn, int NP,
    float* __restrict__ Ofp)
{
    constexpr int WS = 63 * S + K;
    constexpr int BST = CSTG + 8;
    constexpr int MF = MT / 32;                 // m-frags per wave
    __shared__ ushort_t Bsh[WS * BST];
    __shared__ ushort_t Bsl[WS * BST];
    const int tid = threadIdx.x, lane = tid & 63, wid = tid >> 6;
    const int wm = wid & 1, wn = wid >> 1, l15 = lane & 15, quad = lane >> 4;
    const int bx = blockIdx.x, oy = blockIdx.y;
    const int NOC = CoutT / MT;
    const int ocg = blockIdx.z % NOC, b = blockIdx.z / NOC;
    const int ox0 = bx * 64;
    const int ocb = ocg * MT + wm * (MT / 2);

    f32x4 acc[MF][2];
#pragma unroll
    for (int mi = 0; mi < MF; ++mi)
#pragma unroll
        for (int ni = 0; ni < 2; ++ni) acc[mi][ni] = (f32x4){0.f, 0.f, 0.f, 0.f};

#pragma unroll
    for (int ky = 0; ky < K; ++ky) {
        const long rowoff = ((long)(b * Hp + oy * S + ky) * Wp + ox0 * S) * CIN;
        for (int cs = 0; cs < CIN; cs += CSTG) {
            __syncthreads();
            constexpr int NCH = WS * CSTG / 8;
#pragma unroll
            for (int it = 0; it < (NCH + 255) / 256; ++it) {
                int flat = tid + it * 256;
                if (flat < NCH) {
                    int e0 = flat * 8;
                    int x = e0 / CSTG;
                    int c = e0 - x * CSTG;
                    *(int4*)&Bsh[x * BST + c] = *(const int4*)&Xh[rowoff + (long)x * CIN + cs + c];
                    *(int4*)&Bsl[x * BST + c] = *(const int4*)&Xl[rowoff + (long)x * CIN + cs + c];
                }
            }
            __syncthreads();
#pragma unroll
            for (int kx = 0; kx < K; ++kx) {
#pragma unroll
                for (int ic0 = 0; ic0 < CSTG; ic0 += 32) {
                    const long wo = ((long)((ky * K + kx) * CoutT + ocb) * CIN) + cs + ic0 + quad * 8;
                    half8 Ah[MF], Al[MF], Bh[2], Bl[2];
#pragma unroll
                    for (int mi = 0; mi < MF; ++mi) {
                        Ah[mi] = *(const half8*)&Wh[wo + (long)(mi * 16 + l15) * CIN];
                        Al[mi] = *(const half8*)&Wl[wo + (long)(mi * 16 + l15) * CIN];
                    }
#pragma unroll
                    for (int ni = 0; ni < 2; ++ni) {
                        int xl = (wn * 32 + ni * 16 + l15) * S + kx;
                        Bh[ni] = *(const half8*)&Bsh[xl * BST + ic0 + quad * 8];
                        Bl[ni] = *(const half8*)&Bsl[xl * BST + ic0 + quad * 8];
                    }
#pragma unroll
                    for (int mi = 0; mi < MF; ++mi)
#pragma unroll
                        for (int ni = 0; ni < 2; ++ni) {
                            acc[mi][ni] = __builtin_amdgcn_mfma_f32_16x16x32_f16(Ah[mi], Bh[ni], acc[mi][ni], 0, 0, 0);
                            acc[mi][ni] = __builtin_amdgcn_mfma_f32_16x16x32_f16(Al[mi], Bh[ni], acc[mi][ni], 0, 0, 0);
                            acc[mi][ni] = __builtin_amdgcn_mfma_f32_16x16x32_f16(Ah[mi], Bl[ni], acc[mi][ni], 0, 0, 0);
                        }
                }
            }
        }
    }
    // epilogue: bias + relu, write
#pragma unroll
    for (int ni = 0; ni < 2; ++ni) {
        const int n = ox0 + wn * 32 + ni * 16 + l15;
#pragma unroll
        for (int mi = 0; mi < MF; ++mi) {
            const int ocf = ocg * MT + wm * (MT / 2) + mi * 16 + quad * 4;
            float4 bv = *(const float4*)&bias[ocf];
            float v0 = fmaxf(acc[mi][ni][0] + bv.x, 0.f);
            float v1 = fmaxf(acc[mi][ni][1] + bv.y, 0.f);
            float v2 = fmaxf(acc[mi][ni][2] + bv.z, 0.f);
            float v3 = fmaxf(acc[mi][ni][3] + bv.w, 0.f);
            if (WRITE_CL) {
                long o = ((long)(b * Hpn + oy + NP) * Wpn + n + NP) * CoutT + ocf;
                u16x4 hv, lv;
                ushort_t th, tl;
                split16(v0, th, tl); hv[0] = th; lv[0] = tl;
                split16(v1, th, tl); hv[1] = th; lv[1] = tl;
                split16(v2, th, tl); hv[2] = th; lv[2] = tl;
                split16(v3, th, tl); hv[3] = th; lv[3] = tl;
                *(u16x4*)&Oh[o] = hv;
                *(u16x4*)&Ol[o] = lv;
            } else {
                long o = ((long)(b * CoutT + ocf) << 12) + (oy << 6) + n;
                Ofp[o] = v0;
                Ofp[o + 4096] = v1;
                Ofp[o + 8192] = v2;
                Ofp[o + 12288] = v3;
            }
        }
    }
}

// -------- conv5 (256->1, K3 S1 P1) + relu + gate, ic-parallel (4 groups) ----------
__global__ __launch_bounds__(256) void conv5_gate_k(
    const float* __restrict__ s4, const float* __restrict__ w,
    const float* __restrict__ bias, float* __restrict__ gate)
{
    const int tid = threadIdx.x;
    const int lane = tid & 63, g = tid >> 6;
    const int oy = blockIdx.x, b = blockIdx.y;
    int ixo[3], iyo[3];
#pragma unroll
    for (int k = 0; k < 3; ++k) {
        int ix = lane + k - 1; if (ix < 0) ix = -ix; if (ix >= 64) ix = 126 - ix;
        int iy = oy + k - 1; if (iy < 0) iy = -iy; if (iy >= 64) iy = 126 - iy;
        ixo[k] = ix; iyo[k] = iy << 6;
    }
    float part = 0.f;
    const float* inb = s4 + ((long)b * 256 + g * 64) * 4096;
    const float* wg = w + g * 64 * 9;
    for (int ic = 0; ic < 64; ++ic) {
        const float* inc = inb + ic * 4096;
        const float* wc = wg + ic * 9;
#pragma unroll
        for (int ky = 0; ky < 3; ++ky)
#pragma unroll
            for (int kx = 0; kx < 3; ++kx)
                part = fmaf(wc[ky * 3 + kx], inc[iyo[ky] + ixo[kx]], part);
    }
    __shared__ float red[4][64];
    red[g][lane] = part;
    __syncthreads();
    if (tid < 64) {
        float s = bias[0] + red[0][tid] + red[1][tid] + red[2][tid] + red[3][tid];
        s = fmaxf(s, 0.f);
        gate[(b << 12) + (oy << 6) + tid] = tanf(PI_F * (tanhf(s) - 0.5f));
    }
}

// ---------------- invn[b][p] = 1/sqrt(sum_c (F+1e-7)^2) ----------------
__global__ __launch_bounds__(256) void invn_k(const float* __restrict__ F, float* __restrict__ invn)
{
    const int p = blockIdx.x * 256 + threadIdx.x;
    const int b = blockIdx.y;
    const float* Fb = F + (long)b * 524288;
    float ss = 0.f;
#pragma unroll 8
    for (int c = 0; c < 128; ++c) {
        float v = Fb[c * 4096 + p] + 1e-7f;
        ss = fmaf(v, v, ss);
    }
    invn[(b << 12) + p] = 1.0f / sqrtf(ss);
}

// -------- prep: Fo16[b][c][p] = bf16(F), Ft16[b][p][c] = bf16(F^T) ---------------
__global__ __launch_bounds__(256) void prep_bf16_k(
    const float* __restrict__ F, ushort_t* __restrict__ Fo16, ushort_t* __restrict__ Ft16)
{
    __shared__ float Ls[128][65];
    const int tid = threadIdx.x;
    const int lane = tid & 63, wv = tid >> 6;
    const int p0 = blockIdx.x * 64, b = blockIdx.y;
#pragma unroll 8
    for (int cc = 0; cc < 32; ++cc) {
        int c = wv * 32 + cc;
        long idx = ((long)b * 128 + c) * 4096 + p0 + lane;
        float v = F[idx];
        Fo16[idx] = f2bf(v);
        Ls[c][lane] = v;
    }
    __syncthreads();
#pragma unroll 8
    for (int i = 0; i < 32; ++i) {
        int flat = tid + 256 * i;
        int c = flat & 127, pl_ = flat >> 7;
        Ft16[((long)b * 4096 + p0 + pl_) * 128 + c] = f2bf(Ls[c][pl_]);
    }
}

// -------- scores MFMA: 128x128 tile; epilogue fuses invn/gate + softmax stats -----
__global__ __launch_bounds__(256) void scores_mfma_k(
    const ushort_t* __restrict__ Ft16, const float* __restrict__ invn,
    const float* __restrict__ gate, float* __restrict__ scores,
    float* __restrict__ pm, float* __restrict__ pl, int b)
{
    const int tid = threadIdx.x;
    const int lane = tid & 63, wid = tid >> 6;
    const int wm = wid & 1, wn = wid >> 1;
    const int l15 = lane & 15, quad = lane >> 4;
    const int qb = blockIdx.x, pb = blockIdx.y;
    const int p_base = pb * 128 + wm * 64;
    const int q_base = qb * 128 + wn * 64;
    const ushort_t* Fb = Ft16 + (long)b * 4096 * 128;

    f32x4 acc[4][4];
#pragma unroll
    for (int mi = 0; mi < 4; ++mi)
#pragma unroll
        for (int ni = 0; ni < 4; ++ni) acc[mi][ni] = (f32x4){0.f, 0.f, 0.f, 0.f};

#pragma unroll
    for (int c0 = 0; c0 < 128; c0 += 32) {
        short8 A[4], B[4];
#pragma unroll
        for (int mi = 0; mi < 4; ++mi)
            A[mi] = *(const short8*)(Fb + (long)(p_base + mi * 16 + l15) * 128 + c0 + quad * 8);
#pragma unroll
        for (int ni = 0; ni < 4; ++ni)
            B[ni] = *(const short8*)(Fb + (long)(q_base + ni * 16 + l15) * 128 + c0 + quad * 8);
#pragma unroll
        for (int mi = 0; mi < 4; ++mi)
#pragma unroll
            for (int ni = 0; ni < 4; ++ni)
                acc[mi][ni] = __builtin_amdgcn_mfma_f32_16x16x32_bf16(A[mi], B[ni], acc[mi][ni], 0, 0, 0);
    }

    const int bp = b << 12;
    float iv[4][4], gt[4][4];
#pragma unroll
    for (int mi = 0; mi < 4; ++mi)
#pragma unroll
        for (int r = 0; r < 4; ++r) {
            int p = p_base + mi * 16 + quad * 4 + r;
            iv[mi][r] = invn[bp + p];
            gt[mi][r] = gate[bp + p];
        }

    __shared__ float Rm[2][2][64], Rl[2][2][64];
#pragma unroll
    for (int ni = 0; ni < 4; ++ni) {
        const int q = q_base + ni * 16 + l15;
        float mloc = -3.4e38f;
#pragma unroll
        for (int mi = 0; mi < 4; ++mi)
#pragma unroll
            for (int r = 0; r < 4; ++r) {
                float s = fmaf(acc[mi][ni][r], iv[mi][r], gt[mi][r]);
                acc[mi][ni][r] = s;
                mloc = fmaxf(mloc, s);
                int p = p_base + mi * 16 + quad * 4 + r;
                scores[(long)p * 4096 + q] = s;
            }
        mloc = fmaxf(mloc, __shfl_xor(mloc, 16));
        mloc = fmaxf(mloc, __shfl_xor(mloc, 32));
        float lloc = 0.f;
#pragma unroll
        for (int mi = 0; mi < 4; ++mi)
#pragma unroll
            for (int r = 0; r < 4; ++r)
                lloc += __expf(acc[mi][ni][r] - mloc);
        lloc += __shfl_xor(lloc, 16);
        lloc += __shfl_xor(lloc, 32);
        if (quad == 0) {
            Rm[wn][wm][ni * 16 + l15] = mloc;
            Rl[wn][wm][ni * 16 + l15] = lloc;
        }
    }
    __syncthreads();
    if (tid < 128) {
        int wn2 = tid >> 6, qq = tid & 63;
        float ma = Rm[wn2][0][qq], mb2 = Rm[wn2][1][qq];
        float M = fmaxf(ma, mb2);
        float L = Rl[wn2][0][qq] * __expf(ma - M) + Rl[wn2][1][qq] * __expf(mb2 - M);
        pm[pb * 4096 + blockIdx.x * 128 + tid] = M;
        pl[pb * 4096 + blockIdx.x * 128 + tid] = L;
    }
}

// -------- attv MFMA: attP[ks][c][q] = sum_{p in ks slice} exp(s[p][q]-m[q]) * F[c][p]
__global__ __launch_bounds__(256) void attv_mfma_k(
    const float* __restrict__ scores, const ushort_t* __restrict__ Fo16,
    const float* __restrict__ pm, const float* __restrict__ pl,
    float* __restrict__ invl, float* __restrict__ attP, int b)
{
    __shared__ ushort_t Es[64][72];
    __shared__ float Ms[64];
    const int tid = threadIdx.x;
    const int lane = tid & 63, wid = tid >> 6;
    const int wm = wid & 1, wn = wid >> 1;
    const int l15 = lane & 15, quad = lane >> 4;
    const int qb = blockIdx.x, ks = blockIdx.y;
    const int q_base = qb * 64;
    const int m0 = wm * 64, n0 = wn * 32;

    if (tid < 64) {
        int q = q_base + tid;
        float m = -3.4e38f;
#pragma unroll 8
        for (int i = 0; i < 32; ++i) m = fmaxf(m, pm[i * 4096 + q]);
        float l = 0.f;
#pragma unroll 8
        for (int i = 0; i < 32; ++i) l += pl[i * 4096 + q] * __expf(pm[i * 4096 + q] - m);
        Ms[tid] = m;
        if (ks == 0) invl[(b << 12) + q] = 1.0f / l;
    }
    __syncthreads();

    const ushort_t* Fob = Fo16 + (long)b * 128 * 4096;
    f32x4 acc[4][2];
#pragma unroll
    for (int mi = 0; mi < 4; ++mi)
#pragma unroll
        for (int ni = 0; ni < 2; ++ni) acc[mi][ni] = (f32x4){0.f, 0.f, 0.f, 0.f};

    const int p_start = ks * 512;
    for (int pc = p_start; pc < p_start + 512; pc += 64) {
#pragma unroll
        for (int i = 0; i < 4; ++i) {
            int idx = tid + 256 * i;
            int p_l = idx >> 4, qv = (idx & 15) << 2;
            float4 sv = *(const float4*)&scores[(long)(pc + p_l) * 4096 + q_base + qv];
            Es[qv + 0][p_l] = f2bf(__expf(sv.x - Ms[qv + 0]));
            Es[qv + 1][p_l] = f2bf(__expf(sv.y - Ms[qv + 1]));
            Es[qv + 2][p_l] = f2bf(__expf(sv.z - Ms[qv + 2]));
            Es[qv + 3][p_l] = f2bf(__expf(sv.w - Ms[qv + 3]));
        }
        __syncthreads();
#pragma unroll
        for (int ksub = 0; ksub < 2; ++ksub) {
            const int pk = pc + ksub * 32 + quad * 8;
            short8 A[4], B[2];
#pragma unroll
            for (int mi = 0; mi < 4; ++mi)
                A[mi] = *(const short8*)(Fob + (long)(m0 + mi * 16 + l15) * 4096 + pk);
#pragma unroll
            for (int ni = 0; ni < 2; ++ni)
                B[ni] = *(const short8*)&Es[n0 + ni * 16 + l15][ksub * 32 + quad * 8];
#pragma unroll
            for (int mi = 0; mi < 4; ++mi)
#pragma unroll
                for (int ni = 0; ni < 2; ++ni)
                    acc[mi][ni] = __builtin_amdgcn_mfma_f32_16x16x32_bf16(A[mi], B[ni], acc[mi][ni], 0, 0, 0);
        }
        __syncthreads();
    }
#pragma unroll
    for (int mi = 0; mi < 4; ++mi)
#pragma unroll
        for (int ni = 0; ni < 2; ++ni)
#pragma unroll
            for (int r = 0; r < 4; ++r) {
                int c = m0 + mi * 16 + quad * 4 + r;
                int q = q_base + n0 + ni * 16 + l15;
                attP[(long)(ks * 128 + c) * 4096 + q] = acc[mi][ni][r];
            }
}

// ---------------- combiner (per batch) ----------------
__global__ __launch_bounds__(256) void combiner_k(
    const float* __restrict__ attP, const float* __restrict__ F,
    const float* __restrict__ invl, const float* __restrict__ cw,
    const float* __restrict__ cb, float* __restrict__ out, int b)
{
    const int tid = threadIdx.x;
    const int q = blockIdx.x * 256 + tid;
    const int o0 = blockIdx.y << 4;
    float il = invl[(b << 12) + q];
    const float* Fb = F + (long)b * 524288 + q;
    float acc[16];
#pragma unroll
    for (int j = 0; j < 16; ++j) acc[j] = cb[o0 + j];
    for (int c = 0; c < 128; ++c) {
        float a = 0.f;
#pragma unroll
        for (int ks = 0; ks < 8; ++ks)
            a += attP[(long)(ks * 128 + c) * 4096 + q];
        a *= il;
        float f = Fb[(long)c * 4096];
#pragma unroll
        for (int j = 0; j < 16; ++j) {
            acc[j] = fmaf(cw[(o0 + j) * 256 + c], a, acc[j]);
            acc[j] = fmaf(cw[(o0 + j) * 256 + 128 + c], f, acc[j]);
        }
    }
#pragma unroll
    for (int j = 0; j < 16; ++j)
        out[((long)(b * 128 + o0 + j) << 12) + q] = acc[j];
}

// =====================================================================================
extern "C" void kernel_launch(void* const* d_in, const int* in_sizes, int n_in,
                              void* d_out, int out_size, void* d_ws, size_t ws_size,
                              hipStream_t stream)
{
    const float* F     = (const float*)d_in[0];
    const float* imgs  = (const float*)d_in[1];
    const float* masks = (const float*)d_in[2];
    const float* gw1 = (const float*)d_in[3];  const float* gb1 = (const float*)d_in[4];
    const float* gw2 = (const float*)d_in[5];  const float* gb2 = (const float*)d_in[6];
    const float* gw3 = (const float*)d_in[7];  const float* gb3 = (const float*)d_in[8];
    const float* gw4 = (const float*)d_in[9];  const float* gb4 = (const float*)d_in[10];
    const float* gw5 = (const float*)d_in[11]; const float* gb5 = (const float*)d_in[12];
    const float* cw  = (const float*)d_in[13]; const float* cb  = (const float*)d_in[14];
    float* out = (float*)d_out;

    // ---- workspace layout (float offsets), total 35,526,656 fl = 142.1 MB ----
    float* W = (float*)d_ws;
    // region A (17,305,600 fl): Xcl2 h/l -> Xcl4 h/l -> scores
    ushort_t* Xcl2h = (ushort_t*)(W);                 // [8][260][260][32] fp16
    ushort_t* Xcl2l = (ushort_t*)(W + 8652800);
    ushort_t* Xcl4h = (ushort_t*)(W);                 // [8][130][130][128] fp16
    ushort_t* Xcl4l = (ushort_t*)(W + 8652800);
    float*    scores = W;                             // [4096][4096] f32
    // region B (8,921,088 fl): Xcl3 h/l -> Fo16
    ushort_t* Xcl3h = (ushort_t*)(W + 17305600);      // [8][132][132][64] fp16
    ushort_t* Xcl3l = (ushort_t*)(W + 21766144);
    ushort_t* Fo16  = (ushort_t*)(W + 17305600);      // [8][128][4096] bf16
    // region C (8,388,608 fl): s4 -> attP + Ft16
    float*    s4   = W + 26226688;                    // [8][256][64][64] f32
    float*    attP = W + 26226688;                    // [8][128][4096] f32
    ushort_t* Ft16 = (ushort_t*)(W + 30420992);       // [8][4096][128] bf16
    // weights (550,912 fl)
    ushort_t* W2h = (ushort_t*)(W + 34615296);
    ushort_t* W2l = (ushort_t*)(W + 34640896);
    ushort_t* W3h = (ushort_t*)(W + 34666496);
    ushort_t* W3l = (ushort_t*)(W + 34768896);
    ushort_t* W4h = (ushort_t*)(W + 34871296);
    ushort_t* W4l = (ushort_t*)(W + 35018752);
    // persistent smalls
    float* gate = W + 35166208;
    float* invn = W + 35198976;
    float* invl = W + 35231744;
    float* pm   = W + 35264512;                       // [32][4096]
    float* pl   = W + 35395584;

    // ---- weight transforms ----
    transform_w_k<<<dim3(200),  256, 0, stream>>>(gw2, W2h, W2l, 64, 32, 25);
    transform_w_k<<<dim3(800),  256, 0, stream>>>(gw3, W3h, W3l, 128, 64, 25);
    transform_w_k<<<dim3(1152), 256, 0, stream>>>(gw4, W4h, W4l, 256, 128, 9);

    // ---- conv stack ----
    conv1_row_k<<<dim3(4, 16, 32), 256, 0, stream>>>(imgs, masks, gw1, gb1, Xcl2h, Xcl2l);
    pad_cl_k<<<dim3(260, 8), 256, 0, stream>>>(Xcl2h, Xcl2l, 260, 260, 2, 32, 256, 256);
    // conv2: K5 S2, Cin32, Cout64 -> Xcl3 (pad 2)
    conv_mfma_k<5, 2, 32, 32, 64, true><<<dim3(2, 128, 8), 256, 0, stream>>>(
        Xcl2h, Xcl2l, W2h, W2l, gb2, 260, 260, 64, Xcl3h, Xcl3l, 132, 132, 2, nullptr);
    pad_cl_k<<<dim3(132, 8), 256, 0, stream>>>(Xcl3h, Xcl3l, 132, 132, 2, 64, 128, 128);
    // conv3: K5 S1, Cin64, Cout128 -> Xcl4 (pad 1)
    conv_mfma_k<5, 1, 64, 64, 128, true><<<dim3(2, 128, 8), 256, 0, stream>>>(
        Xcl3h, Xcl3l, W3h, W3l, gb3, 132, 132, 128, Xcl4h, Xcl4l, 130, 130, 1, nullptr);
    pad_cl_k<<<dim3(130, 8), 256, 0, stream>>>(Xcl4h, Xcl4l, 130, 130, 1, 128, 128, 128);
    // conv4: K3 S2, Cin128, Cout256 -> s4 planar f32
    conv_mfma_k<3, 2, 128, 64, 128, false><<<dim3(1, 64, 16), 256, 0, stream>>>(
        Xcl4h, Xcl4l, W4h, W4l, gb4, 130, 130, 256, nullptr, nullptr, 0, 0, 0, s4);
    conv5_gate_k<<<dim3(64, 8), 256, 0, stream>>>(s4, gw5, gb5, gate);

    // ---- attention prep ----
    invn_k<<<dim3(16, 8), 256, 0, stream>>>(F, invn);
    prep_bf16_k<<<dim3(64, 8), 256, 0, stream>>>(F, Fo16, Ft16);

    // ---- per-batch attention (MFMA) ----
    for (int b = 0; b < 8; ++b) {
        scores_mfma_k<<<dim3(32, 32), 256, 0, stream>>>(Ft16, invn, gate, scores, pm, pl, b);
        attv_mfma_k<<<dim3(64, 8), 256, 0, stream>>>(scores, Fo16, pm, pl, invl, attP, b);
        combiner_k<<<dim3(16, 8), 256, 0, stream>>>(attP, F, invl, cw, cb, out, b);
    }
}

// Round 7
// 1137.345 us; speedup vs baseline: 4.1689x; 1.7257x over previous
//
#include <hip/hip_runtime.h>
#include <hip/hip_bf16.h>
#include <hip/hip_fp16.h>
#include <math.h>

// GatedAttention R7: flash-merged attention (one kernel, online column-softmax,
// no scores buffer) + N=128 conv tiles (2x MFMA per weight load).
// Convs: split-fp16 (hi+lo) MFMA, fp32-equivalent. Attention GEMMs bf16.

#define PI_F 3.1415926f

typedef __attribute__((ext_vector_type(8))) short short8;
typedef __attribute__((ext_vector_type(4))) float f32x4;
typedef _Float16 half8 __attribute__((ext_vector_type(8)));
typedef __attribute__((ext_vector_type(4))) unsigned short u16x4;
typedef __attribute__((ext_vector_type(8))) unsigned short u16x8;
typedef unsigned short ushort_t;

__device__ __forceinline__ ushort_t f2bf(float x) {
    unsigned u = __float_as_uint(x);
    unsigned r = (u + 0x7FFFu + ((u >> 16) & 1u)) >> 16;
    return (ushort_t)r;
}
__device__ __forceinline__ void split16(float x, ushort_t& h, ushort_t& l) {
    __half hh = __float2half(x);
    h = __half_as_ushort(hh);
    l = __half_as_ushort(__float2half(x - __half2float(hh)));
}

// ---------------- weight transform: OIHW fp32 -> [ky*kx][oc][ic] fp16 hi/lo --------
__global__ __launch_bounds__(256) void transform_w_k(
    const float* __restrict__ w, ushort_t* __restrict__ Wh, ushort_t* __restrict__ Wl,
    int Cout, int Cin, int KK)
{
    int idx = blockIdx.x * 256 + threadIdx.x;
    int N = Cout * Cin * KK;
    if (idx >= N) return;
    int oc = idx / (Cin * KK);
    int rem = idx - oc * Cin * KK;
    int ic = rem / KK;
    int t = rem - ic * KK;
    float v = w[idx];
    long dst = ((long)t * Cout + oc) * Cin + ic;
    split16(v, Wh[dst], Wl[dst]);
}

// ------- pad-fill for channel-last reflect-padded buffers ----
__global__ __launch_bounds__(256) void pad_cl_k(
    ushort_t* __restrict__ Xh, ushort_t* __restrict__ Xl,
    int Hp, int Wp, int PAD, int C, int H, int W)
{
    const int iy = blockIdx.x, b = blockIdx.y;
    int t = iy - PAD; if (t < 0) t = -t; if (t >= H) t = 2 * H - 2 - t;
    const int iys = t + PAD;
    const long rowd = ((long)(b * Hp + iy) * Wp) * C;
    const long rows = ((long)(b * Hp + iys) * Wp) * C;
    const int nch = Wp * (C >> 3);
    for (int idx = threadIdx.x; idx < nch; idx += 256) {
        int x = idx / (C >> 3);
        int cg = (idx - x * (C >> 3)) << 3;
        int t2 = x - PAD; if (t2 < 0) t2 = -t2; if (t2 >= W) t2 = 2 * W - 2 - t2;
        int xs = t2 + PAD;
        if (xs == x && iys == iy) continue;
        *(int4*)&Xh[rowd + (long)x * C + cg] = *(const int4*)&Xh[rows + (long)xs * C + cg];
        *(int4*)&Xl[rowd + (long)x * C + cg] = *(const int4*)&Xl[rows + (long)xs * C + cg];
    }
}

// ---------------- conv1 (VALU, K7 S1 P3) -> channel-last fp16 h/l ---------
__global__ __launch_bounds__(256) void conv1_row_k(
    const float* __restrict__ imgs, const float* __restrict__ masks,
    const float* __restrict__ w, const float* __restrict__ bias,
    ushort_t* __restrict__ Oh, ushort_t* __restrict__ Ol)
{
    constexpr int K = 7, PAD = 3, NR = 10;
    const int lane = threadIdx.x & 63, wv = threadIdx.x >> 6;
    const int ox = blockIdx.x * 64 + lane;
    const int oy0 = blockIdx.y * 16 + wv * 4;
    const int ocg = blockIdx.z & 3, b = blockIdx.z >> 2;
    const int oc0 = ocg << 3;
    int ixo[K];
#pragma unroll
    for (int kx = 0; kx < K; ++kx) {
        int ix = ox + kx - PAD; if (ix < 0) ix = -ix; if (ix >= 256) ix = 510 - ix;
        ixo[kx] = ix;
    }
    int iyo[NR];
#pragma unroll
    for (int j = 0; j < NR; ++j) {
        int iy = oy0 + j - PAD; if (iy < 0) iy = -iy; if (iy >= 256) iy = 510 - iy;
        iyo[j] = iy << 8;
    }
    float acc[4][8];
#pragma unroll
    for (int oc = 0; oc < 8; ++oc) {
        float bv = bias[oc0 + oc];
#pragma unroll
        for (int r = 0; r < 4; ++r) acc[r][oc] = bv;
    }
    const int HW = 65536;
#pragma unroll
    for (int ic = 0; ic < 4; ++ic) {
        const float* p = (ic < 3) ? (imgs + (b * 3 + ic) * HW) : (masks + b * HW);
#pragma unroll
        for (int j = 0; j < NR; ++j) {
            float row[K];
#pragma unroll
            for (int kx = 0; kx < K; ++kx) row[kx] = p[iyo[j] + ixo[kx]];
#pragma unroll
            for (int r = 0; r < 4; ++r) {
                const int ky = j - r;
                if (ky >= 0 && ky < K) {
#pragma unroll
                    for (int oc = 0; oc < 8; ++oc) {
                        const float* wc = w + ((oc0 + oc) * 4 + ic) * 49 + ky * K;
#pragma unroll
                        for (int kx = 0; kx < K; ++kx)
                            acc[r][oc] = fmaf(wc[kx], row[kx], acc[r][oc]);
                    }
                }
            }
        }
    }
#pragma unroll
    for (int r = 0; r < 4; ++r) {
        long o = ((long)(b * 260 + oy0 + r + 2) * 260 + ox + 2) * 32 + oc0;
        u16x8 hv, lv;
#pragma unroll
        for (int oc = 0; oc < 8; ++oc) {
            float v = fmaxf(acc[r][oc], 0.f);
            ushort_t h, l;
            split16(v, h, l);
            hv[oc] = h; lv[oc] = l;
        }
        *(u16x8*)&Oh[o] = hv;
        *(u16x8*)&Ol[o] = lv;
    }
}

// ------- generic MFMA conv (split-fp16), tile MT oc x (32*NF) px ----------
template<int K, int S, int CIN, int CSTG, int MT, int NF, bool WRITE_CL>
__global__ __launch_bounds__(256) void conv_mfma_k(
    const ushort_t* __restrict__ Xh, const ushort_t* __restrict__ Xl,
    const ushort_t* __restrict__ Wh, const ushort_t* __restrict__ Wl,
    const float* __restrict__ bias,
    int Hp, int Wp, int CoutT,
    ushort_t* __restrict__ Oh, ushort_t* __restrict__ Ol, int Hpn, int Wpn, int NP,
    float* __restrict__ Ofp)
{
    constexpr int NPX = 32 * NF;                // px per block
    constexpr int WS = (NPX - 1) * S + K;
    constexpr int BST = CSTG + 8;
    constexpr int MF = MT / 32;
    __shared__ ushort_t Bsh[WS * BST];
    __shared__ ushort_t Bsl[WS * BST];
    const int tid = threadIdx.x, lane = tid & 63, wid = tid >> 6;
    const int wm = wid & 1, wn = wid >> 1, l15 = lane & 15, quad = lane >> 4;
    const int bx = blockIdx.x, oy = blockIdx.y;
    const int NOC = CoutT / MT;
    const int ocg = blockIdx.z % NOC, b = blockIdx.z / NOC;
    const int ox0 = bx * NPX;
    const int ocb = ocg * MT + wm * (MT / 2);

    f32x4 acc[MF][NF];
#pragma unroll
    for (int mi = 0; mi < MF; ++mi)
#pragma unroll
        for (int ni = 0; ni < NF; ++ni) acc[mi][ni] = (f32x4){0.f, 0.f, 0.f, 0.f};

#pragma unroll
    for (int ky = 0; ky < K; ++ky) {
        const long rowoff = ((long)(b * Hp + oy * S + ky) * Wp + ox0 * S) * CIN;
        for (int cs = 0; cs < CIN; cs += CSTG) {
            __syncthreads();
            constexpr int NCH = WS * CSTG / 8;
#pragma unroll
            for (int it = 0; it < (NCH + 255) / 256; ++it) {
                int flat = tid + it * 256;
                if (flat < NCH) {
                    int e0 = flat * 8;
                    int x = e0 / CSTG;
                    int c = e0 - x * CSTG;
                    *(int4*)&Bsh[x * BST + c] = *(const int4*)&Xh[rowoff + (long)x * CIN + cs + c];
                    *(int4*)&Bsl[x * BST + c] = *(const int4*)&Xl[rowoff + (long)x * CIN + cs + c];
                }
            }
            __syncthreads();
#pragma unroll
            for (int kx = 0; kx < K; ++kx) {
#pragma unroll
                for (int ic0 = 0; ic0 < CSTG; ic0 += 32) {
                    const long wo = ((long)((ky * K + kx) * CoutT + ocb) * CIN) + cs + ic0 + quad * 8;
                    half8 Ah[MF], Al[MF], Bh[NF], Bl[NF];
#pragma unroll
                    for (int mi = 0; mi < MF; ++mi) {
                        Ah[mi] = *(const half8*)&Wh[wo + (long)(mi * 16 + l15) * CIN];
                        Al[mi] = *(const half8*)&Wl[wo + (long)(mi * 16 + l15) * CIN];
                    }
#pragma unroll
                    for (int ni = 0; ni < NF; ++ni) {
                        int xl = (wn * (16 * NF) + ni * 16 + l15) * S + kx;
                        Bh[ni] = *(const half8*)&Bsh[xl * BST + ic0 + quad * 8];
                        Bl[ni] = *(const half8*)&Bsl[xl * BST + ic0 + quad * 8];
                    }
#pragma unroll
                    for (int mi = 0; mi < MF; ++mi)
#pragma unroll
                        for (int ni = 0; ni < NF; ++ni) {
                            acc[mi][ni] = __builtin_amdgcn_mfma_f32_16x16x32_f16(Ah[mi], Bh[ni], acc[mi][ni], 0, 0, 0);
                            acc[mi][ni] = __builtin_amdgcn_mfma_f32_16x16x32_f16(Al[mi], Bh[ni], acc[mi][ni], 0, 0, 0);
                            acc[mi][ni] = __builtin_amdgcn_mfma_f32_16x16x32_f16(Ah[mi], Bl[ni], acc[mi][ni], 0, 0, 0);
                        }
                }
            }
        }
    }
#pragma unroll
    for (int ni = 0; ni < NF; ++ni) {
        const int n = ox0 + wn * (16 * NF) + ni * 16 + l15;
#pragma unroll
        for (int mi = 0; mi < MF; ++mi) {
            const int ocf = ocg * MT + wm * (MT / 2) + mi * 16 + quad * 4;
            float4 bv = *(const float4*)&bias[ocf];
            float v0 = fmaxf(acc[mi][ni][0] + bv.x, 0.f);
            float v1 = fmaxf(acc[mi][ni][1] + bv.y, 0.f);
            float v2 = fmaxf(acc[mi][ni][2] + bv.z, 0.f);
            float v3 = fmaxf(acc[mi][ni][3] + bv.w, 0.f);
            if (WRITE_CL) {
                long o = ((long)(b * Hpn + oy + NP) * Wpn + n + NP) * CoutT + ocf;
                u16x4 hv, lv;
                ushort_t th, tl;
                split16(v0, th, tl); hv[0] = th; lv[0] = tl;
                split16(v1, th, tl); hv[1] = th; lv[1] = tl;
                split16(v2, th, tl); hv[2] = th; lv[2] = tl;
                split16(v3, th, tl); hv[3] = th; lv[3] = tl;
                *(u16x4*)&Oh[o] = hv;
                *(u16x4*)&Ol[o] = lv;
            } else {
                long o = ((long)(b * CoutT + ocf) << 12) + (oy << 6) + n;
                Ofp[o] = v0;
                Ofp[o + 4096] = v1;
                Ofp[o + 8192] = v2;
                Ofp[o + 12288] = v3;
            }
        }
    }
}

// -------- conv5 (256->1, K3 S1 P1) + relu + gate ----------
__global__ __launch_bounds__(256) void conv5_gate_k(
    const float* __restrict__ s4, const float* __restrict__ w,
    const float* __restrict__ bias, float* __restrict__ gate)
{
    const int tid = threadIdx.x;
    const int lane = tid & 63, g = tid >> 6;
    const int oy = blockIdx.x, b = blockIdx.y;
    int ixo[3], iyo[3];
#pragma unroll
    for (int k = 0; k < 3; ++k) {
        int ix = lane + k - 1; if (ix < 0) ix = -ix; if (ix >= 64) ix = 126 - ix;
        int iy = oy + k - 1; if (iy < 0) iy = -iy; if (iy >= 64) iy = 126 - iy;
        ixo[k] = ix; iyo[k] = iy << 6;
    }
    float part = 0.f;
    const float* inb = s4 + ((long)b * 256 + g * 64) * 4096;
    const float* wg = w + g * 64 * 9;
    for (int ic = 0; ic < 64; ++ic) {
        const float* inc = inb + ic * 4096;
        const float* wc = wg + ic * 9;
#pragma unroll
        for (int ky = 0; ky < 3; ++ky)
#pragma unroll
            for (int kx = 0; kx < 3; ++kx)
                part = fmaf(wc[ky * 3 + kx], inc[iyo[ky] + ixo[kx]], part);
    }
    __shared__ float red[4][64];
    red[g][lane] = part;
    __syncthreads();
    if (tid < 64) {
        float s = bias[0] + red[0][tid] + red[1][tid] + red[2][tid] + red[3][tid];
        s = fmaxf(s, 0.f);
        gate[(b << 12) + (oy << 6) + tid] = tanf(PI_F * (tanhf(s) - 0.5f));
    }
}

// ---------------- invn[b][p] = 1/sqrt(sum_c (F+1e-7)^2) ----------------
__global__ __launch_bounds__(256) void invn_k(const float* __restrict__ F, float* __restrict__ invn)
{
    const int p = blockIdx.x * 256 + threadIdx.x;
    const int b = blockIdx.y;
    const float* Fb = F + (long)b * 524288;
    float ss = 0.f;
#pragma unroll 8
    for (int c = 0; c < 128; ++c) {
        float v = Fb[c * 4096 + p] + 1e-7f;
        ss = fmaf(v, v, ss);
    }
    invn[(b << 12) + p] = 1.0f / sqrtf(ss);
}

// -------- prep: Fo16[b][c][p] = bf16(F), Ft16[b][p][c] = bf16(F^T) ---------------
__global__ __launch_bounds__(256) void prep_bf16_k(
    const float* __restrict__ F, ushort_t* __restrict__ Fo16, ushort_t* __restrict__ Ft16)
{
    __shared__ float Ls[128][65];
    const int tid = threadIdx.x;
    const int lane = tid & 63, wv = tid >> 6;
    const int p0 = blockIdx.x * 64, b = blockIdx.y;
#pragma unroll 8
    for (int cc = 0; cc < 32; ++cc) {
        int c = wv * 32 + cc;
        long idx = ((long)b * 128 + c) * 4096 + p0 + lane;
        float v = F[idx];
        Fo16[idx] = f2bf(v);
        Ls[c][lane] = v;
    }
    __syncthreads();
#pragma unroll 8
    for (int i = 0; i < 32; ++i) {
        int flat = tid + 256 * i;
        int c = flat & 127, pl_ = flat >> 7;
        Ft16[((long)b * 4096 + p0 + pl_) * 128 + c] = f2bf(Ls[c][pl_]);
    }
}

// -------- flash attention: per block = 64 q cols, online softmax over all 4096 p ----
// S[p][q] = invn[p]*<F(:,p),F(:,q)> + gate[p];  att[c][q] = sum_p exp(S-m)/l * F[c][p]
__global__ __launch_bounds__(256) void flash_attn_k(
    const ushort_t* __restrict__ Ft16, const ushort_t* __restrict__ Fo16,
    const float* __restrict__ invn, const float* __restrict__ gate,
    float* __restrict__ att)
{
    __shared__ float m_run[64], l_run[64], alphaS[64];
    __shared__ float redM[4][64], redS[4][64];
    __shared__ ushort_t Es[64][72];
    const int tid = threadIdx.x, lane = tid & 63, w = tid >> 6;
    const int l15 = lane & 15, quad = lane >> 4;
    const int q0 = blockIdx.x * 64, b = blockIdx.y;
    const int bp = b << 12;
    const ushort_t* Ftb = Ft16 + (long)b * 4096 * 128;
    const ushort_t* Fob = Fo16 + (long)b * 128 * 4096;

    // hoist q-side B frags (k = c)
    short8 Bq[4][4];
#pragma unroll
    for (int ni = 0; ni < 4; ++ni)
#pragma unroll
        for (int cs = 0; cs < 4; ++cs)
            Bq[ni][cs] = *(const short8*)&Ftb[(long)(q0 + ni * 16 + l15) * 128 + cs * 32 + quad * 8];

    f32x4 O[2][4];
#pragma unroll
    for (int mi = 0; mi < 2; ++mi)
#pragma unroll
        for (int ni = 0; ni < 4; ++ni) O[mi][ni] = (f32x4){0.f, 0.f, 0.f, 0.f};
    if (tid < 64) { m_run[tid] = -3.4e38f; l_run[tid] = 0.f; }

    for (int p0 = 0; p0 < 4096; p0 += 64) {
        __syncthreads();                                   // bar D (Es/red WAR + init)
        // ---- S-GEMM: this wave's 16 p-rows x 64 q
        f32x4 Sa[4];
#pragma unroll
        for (int ni = 0; ni < 4; ++ni) Sa[ni] = (f32x4){0.f, 0.f, 0.f, 0.f};
#pragma unroll
        for (int cs = 0; cs < 4; ++cs) {
            short8 Ap = *(const short8*)&Ftb[(long)(p0 + w * 16 + l15) * 128 + cs * 32 + quad * 8];
#pragma unroll
            for (int ni = 0; ni < 4; ++ni)
                Sa[ni] = __builtin_amdgcn_mfma_f32_16x16x32_bf16(Ap, Bq[ni][cs], Sa[ni], 0, 0, 0);
        }
        float4 iv = *(const float4*)&invn[bp + p0 + w * 16 + quad * 4];
        float4 gt = *(const float4*)&gate[bp + p0 + w * 16 + quad * 4];
        float mx[4];
#pragma unroll
        for (int ni = 0; ni < 4; ++ni) {
            Sa[ni][0] = fmaf(Sa[ni][0], iv.x, gt.x);
            Sa[ni][1] = fmaf(Sa[ni][1], iv.y, gt.y);
            Sa[ni][2] = fmaf(Sa[ni][2], iv.z, gt.z);
            Sa[ni][3] = fmaf(Sa[ni][3], iv.w, gt.w);
            float m = fmaxf(fmaxf(Sa[ni][0], Sa[ni][1]), fmaxf(Sa[ni][2], Sa[ni][3]));
            m = fmaxf(m, __shfl_xor(m, 16));
            m = fmaxf(m, __shfl_xor(m, 32));
            mx[ni] = m;
        }
        if (quad == 0)
#pragma unroll
            for (int ni = 0; ni < 4; ++ni) redM[w][ni * 16 + l15] = mx[ni];
        __syncthreads();                                   // bar A
        if (tid < 64) {
            float mt = fmaxf(fmaxf(redM[0][tid], redM[1][tid]), fmaxf(redM[2][tid], redM[3][tid]));
            float mo = m_run[tid];
            float mn = fmaxf(mo, mt);
            alphaS[tid] = __expf(mo - mn);
            m_run[tid] = mn;
        }
        __syncthreads();                                   // bar B
        // ---- E = exp(S - m), stage to LDS (B-operand [q][p]), column sums
        float sm[4];
#pragma unroll
        for (int ni = 0; ni < 4; ++ni) {
            float mn = m_run[ni * 16 + l15];
            float e0 = __expf(Sa[ni][0] - mn);
            float e1 = __expf(Sa[ni][1] - mn);
            float e2 = __expf(Sa[ni][2] - mn);
            float e3 = __expf(Sa[ni][3] - mn);
            u16x4 ev; ev[0] = f2bf(e0); ev[1] = f2bf(e1); ev[2] = f2bf(e2); ev[3] = f2bf(e3);
            *(u16x4*)&Es[ni * 16 + l15][w * 16 + quad * 4] = ev;
            float sl = (e0 + e1) + (e2 + e3);
            sl += __shfl_xor(sl, 16);
            sl += __shfl_xor(sl, 32);
            sm[ni] = sl;
        }
        if (quad == 0)
#pragma unroll
            for (int ni = 0; ni < 4; ++ni) redS[w][ni * 16 + l15] = sm[ni];
        __syncthreads();                                   // bar C
        if (tid < 64)
            l_run[tid] = l_run[tid] * alphaS[tid] +
                         ((redS[0][tid] + redS[1][tid]) + (redS[2][tid] + redS[3][tid]));
        // ---- O rescale + O-GEMM (c = w*32..w*32+32)
        float al[4];
#pragma unroll
        for (int ni = 0; ni < 4; ++ni) al[ni] = alphaS[ni * 16 + l15];
#pragma unroll
        for (int mi = 0; mi < 2; ++mi)
#pragma unroll
            for (int ni = 0; ni < 4; ++ni) {
                O[mi][ni][0] *= al[ni]; O[mi][ni][1] *= al[ni];
                O[mi][ni][2] *= al[ni]; O[mi][ni][3] *= al[ni];
            }
#pragma unroll
        for (int ks = 0; ks < 2; ++ks) {
            short8 Ac[2], Be[4];
#pragma unroll
            for (int mi = 0; mi < 2; ++mi)
                Ac[mi] = *(const short8*)&Fob[(long)(w * 32 + mi * 16 + l15) * 4096 + p0 + ks * 32 + quad * 8];
#pragma unroll
            for (int ni = 0; ni < 4; ++ni)
                Be[ni] = *(const short8*)&Es[ni * 16 + l15][ks * 32 + quad * 8];
#pragma unroll
            for (int mi = 0; mi < 2; ++mi)
#pragma unroll
                for (int ni = 0; ni < 4; ++ni)
                    O[mi][ni] = __builtin_amdgcn_mfma_f32_16x16x32_bf16(Ac[mi], Be[ni], O[mi][ni], 0, 0, 0);
        }
    }
    __syncthreads();                                       // l_run final visible
    float il[4];
#pragma unroll
    for (int ni = 0; ni < 4; ++ni) il[ni] = 1.0f / l_run[ni * 16 + l15];
#pragma unroll
    for (int mi = 0; mi < 2; ++mi)
#pragma unroll
        for (int ni = 0; ni < 4; ++ni) {
            int c = w * 32 + mi * 16 + quad * 4;
            int q = q0 + ni * 16 + l15;
#pragma unroll
            for (int r = 0; r < 4; ++r)
                att[((long)(b * 128 + c + r) << 12) + q] = O[mi][ni][r] * il[ni];
        }
}

// ---------------- combiner, all batches: out = cwA*att + cwF*F + cb --------
__global__ __launch_bounds__(256) void combiner_k(
    const float* __restrict__ att, const float* __restrict__ F,
    const float* __restrict__ cw, const float* __restrict__ cb,
    float* __restrict__ out)
{
    const int tid = threadIdx.x;
    const int q = blockIdx.x * 256 + tid;
    const int o0 = blockIdx.y << 4;
    const int b = blockIdx.z;
    const float* Ab = att + (long)b * 524288 + q;
    const float* Fb = F + (long)b * 524288 + q;
    float acc[16];
#pragma unroll
    for (int j = 0; j < 16; ++j) acc[j] = cb[o0 + j];
    for (int c = 0; c < 128; ++c) {
        float a = Ab[(long)c * 4096];
        float f = Fb[(long)c * 4096];
#pragma unroll
        for (int j = 0; j < 16; ++j) {
            acc[j] = fmaf(cw[(o0 + j) * 256 + c], a, acc[j]);
            acc[j] = fmaf(cw[(o0 + j) * 256 + 128 + c], f, acc[j]);
        }
    }
#pragma unroll
    for (int j = 0; j < 16; ++j)
        out[((long)(b * 128 + o0 + j) << 12) + q] = acc[j];
}

// =====================================================================================
extern "C" void kernel_launch(void* const* d_in, const int* in_sizes, int n_in,
                              void* d_out, int out_size, void* d_ws, size_t ws_size,
                              hipStream_t stream)
{
    const float* F     = (const float*)d_in[0];
    const float* imgs  = (const float*)d_in[1];
    const float* masks = (const float*)d_in[2];
    const float* gw1 = (const float*)d_in[3];  const float* gb1 = (const float*)d_in[4];
    const float* gw2 = (const float*)d_in[5];  const float* gb2 = (const float*)d_in[6];
    const float* gw3 = (const float*)d_in[7];  const float* gb3 = (const float*)d_in[8];
    const float* gw4 = (const float*)d_in[9];  const float* gb4 = (const float*)d_in[10];
    const float* gw5 = (const float*)d_in[11]; const float* gb5 = (const float*)d_in[12];
    const float* cw  = (const float*)d_in[13]; const float* cb  = (const float*)d_in[14];
    float* out = (float*)d_out;

    // ---- workspace layout (float offsets), ~142 MB ----
    float* W = (float*)d_ws;
    ushort_t* Xcl2h = (ushort_t*)(W);                 // [8][260][260][32] fp16
    ushort_t* Xcl2l = (ushort_t*)(W + 8652800);
    ushort_t* Xcl4h = (ushort_t*)(W);                 // [8][130][130][128] fp16
    ushort_t* Xcl4l = (ushort_t*)(W + 8652800);
    ushort_t* Xcl3h = (ushort_t*)(W + 17305600);      // [8][132][132][64] fp16
    ushort_t* Xcl3l = (ushort_t*)(W + 21766144);
    ushort_t* Fo16  = (ushort_t*)(W + 17305600);      // [8][128][4096] bf16 (after conv3)
    float*    s4   = W + 26226688;                    // [8][256][64][64] f32
    float*    att  = W + 26226688;                    // [8][128][4096] f32 (after conv5)
    ushort_t* Ft16 = (ushort_t*)(W + 30420992);       // [8][4096][128] bf16 (after conv5)
    ushort_t* W2h = (ushort_t*)(W + 34615296);
    ushort_t* W2l = (ushort_t*)(W + 34640896);
    ushort_t* W3h = (ushort_t*)(W + 34666496);
    ushort_t* W3l = (ushort_t*)(W + 34768896);
    ushort_t* W4h = (ushort_t*)(W + 34871296);
    ushort_t* W4l = (ushort_t*)(W + 35018752);
    float* gate = W + 35166208;
    float* invn = W + 35198976;

    // ---- weight transforms ----
    transform_w_k<<<dim3(200),  256, 0, stream>>>(gw2, W2h, W2l, 64, 32, 25);
    transform_w_k<<<dim3(800),  256, 0, stream>>>(gw3, W3h, W3l, 128, 64, 25);
    transform_w_k<<<dim3(1152), 256, 0, stream>>>(gw4, W4h, W4l, 256, 128, 9);

    // ---- conv stack ----
    conv1_row_k<<<dim3(4, 16, 32), 256, 0, stream>>>(imgs, masks, gw1, gb1, Xcl2h, Xcl2l);
    pad_cl_k<<<dim3(260, 8), 256, 0, stream>>>(Xcl2h, Xcl2l, 260, 260, 2, 32, 256, 256);
    conv_mfma_k<5, 2, 32, 32, 64, 4, true><<<dim3(1, 128, 8), 256, 0, stream>>>(
        Xcl2h, Xcl2l, W2h, W2l, gb2, 260, 260, 64, Xcl3h, Xcl3l, 132, 132, 2, nullptr);
    pad_cl_k<<<dim3(132, 8), 256, 0, stream>>>(Xcl3h, Xcl3l, 132, 132, 2, 64, 128, 128);
    conv_mfma_k<5, 1, 64, 64, 128, 4, true><<<dim3(1, 128, 8), 256, 0, stream>>>(
        Xcl3h, Xcl3l, W3h, W3l, gb3, 132, 132, 128, Xcl4h, Xcl4l, 130, 130, 1, nullptr);
    pad_cl_k<<<dim3(130, 8), 256, 0, stream>>>(Xcl4h, Xcl4l, 130, 130, 1, 128, 128, 128);
    conv_mfma_k<3, 2, 128, 64, 128, 2, false><<<dim3(1, 64, 16), 256, 0, stream>>>(
        Xcl4h, Xcl4l, W4h, W4l, gb4, 130, 130, 256, nullptr, nullptr, 0, 0, 0, s4);
    conv5_gate_k<<<dim3(64, 8), 256, 0, stream>>>(s4, gw5, gb5, gate);

    // ---- attention ----
    invn_k<<<dim3(16, 8), 256, 0, stream>>>(F, invn);
    prep_bf16_k<<<dim3(64, 8), 256, 0, stream>>>(F, Fo16, Ft16);
    flash_attn_k<<<dim3(64, 8), 256, 0, stream>>>(Ft16, Fo16, invn, gate, att);
    combiner_k<<<dim3(16, 8, 8), 256, 0, stream>>>(att, F, cw, cb, out);
}

// Round 8
// 952.109 us; speedup vs baseline: 4.9800x; 1.1946x over previous
//
#include <hip/hip_runtime.h>
#include <hip/hip_bf16.h>
#include <hip/hip_fp16.h>
#include <math.h>

// GatedAttention R8: conv MFMA kernels now stage BOTH operands (input rows AND
// weights) through LDS per (ky,cs) phase -> inner loop is pure LDS reads + MFMA
// (R7 loaded weight frags from global inside the loop: ~300cyc/step stalls,
// MfmaUtil 23%). MT=64 tiles (NOC split), CSTG=32. Split-fp16 numerics unchanged.
// Attention = R7 flash (passed, absmax 0.0078).

#define PI_F 3.1415926f

typedef __attribute__((ext_vector_type(8))) short short8;
typedef __attribute__((ext_vector_type(4))) float f32x4;
typedef _Float16 half8 __attribute__((ext_vector_type(8)));
typedef __attribute__((ext_vector_type(4))) unsigned short u16x4;
typedef __attribute__((ext_vector_type(8))) unsigned short u16x8;
typedef unsigned short ushort_t;

__device__ __forceinline__ ushort_t f2bf(float x) {
    unsigned u = __float_as_uint(x);
    unsigned r = (u + 0x7FFFu + ((u >> 16) & 1u)) >> 16;
    return (ushort_t)r;
}
__device__ __forceinline__ void split16(float x, ushort_t& h, ushort_t& l) {
    __half hh = __float2half(x);
    h = __half_as_ushort(hh);
    l = __half_as_ushort(__float2half(x - __half2float(hh)));
}

// ---------------- weight transform: OIHW fp32 -> [ky*kx][oc][ic] fp16 hi/lo --------
__global__ __launch_bounds__(256) void transform_w_k(
    const float* __restrict__ w, ushort_t* __restrict__ Wh, ushort_t* __restrict__ Wl,
    int Cout, int Cin, int KK)
{
    int idx = blockIdx.x * 256 + threadIdx.x;
    int N = Cout * Cin * KK;
    if (idx >= N) return;
    int oc = idx / (Cin * KK);
    int rem = idx - oc * Cin * KK;
    int ic = rem / KK;
    int t = rem - ic * KK;
    float v = w[idx];
    long dst = ((long)t * Cout + oc) * Cin + ic;
    split16(v, Wh[dst], Wl[dst]);
}

// ------- pad-fill for channel-last reflect-padded buffers ----
__global__ __launch_bounds__(256) void pad_cl_k(
    ushort_t* __restrict__ Xh, ushort_t* __restrict__ Xl,
    int Hp, int Wp, int PAD, int C, int H, int W)
{
    const int iy = blockIdx.x, b = blockIdx.y;
    int t = iy - PAD; if (t < 0) t = -t; if (t >= H) t = 2 * H - 2 - t;
    const int iys = t + PAD;
    const long rowd = ((long)(b * Hp + iy) * Wp) * C;
    const long rows = ((long)(b * Hp + iys) * Wp) * C;
    const int nch = Wp * (C >> 3);
    for (int idx = threadIdx.x; idx < nch; idx += 256) {
        int x = idx / (C >> 3);
        int cg = (idx - x * (C >> 3)) << 3;
        int t2 = x - PAD; if (t2 < 0) t2 = -t2; if (t2 >= W) t2 = 2 * W - 2 - t2;
        int xs = t2 + PAD;
        if (xs == x && iys == iy) continue;
        *(int4*)&Xh[rowd + (long)x * C + cg] = *(const int4*)&Xh[rows + (long)xs * C + cg];
        *(int4*)&Xl[rowd + (long)x * C + cg] = *(const int4*)&Xl[rows + (long)xs * C + cg];
    }
}

// ---------------- conv1 (VALU, K7 S1 P3) -> channel-last fp16 h/l ---------
__global__ __launch_bounds__(256) void conv1_row_k(
    const float* __restrict__ imgs, const float* __restrict__ masks,
    const float* __restrict__ w, const float* __restrict__ bias,
    ushort_t* __restrict__ Oh, ushort_t* __restrict__ Ol)
{
    constexpr int K = 7, PAD = 3, NR = 10;
    const int lane = threadIdx.x & 63, wv = threadIdx.x >> 6;
    const int ox = blockIdx.x * 64 + lane;
    const int oy0 = blockIdx.y * 16 + wv * 4;
    const int ocg = blockIdx.z & 3, b = blockIdx.z >> 2;
    const int oc0 = ocg << 3;
    int ixo[K];
#pragma unroll
    for (int kx = 0; kx < K; ++kx) {
        int ix = ox + kx - PAD; if (ix < 0) ix = -ix; if (ix >= 256) ix = 510 - ix;
        ixo[kx] = ix;
    }
    int iyo[NR];
#pragma unroll
    for (int j = 0; j < NR; ++j) {
        int iy = oy0 + j - PAD; if (iy < 0) iy = -iy; if (iy >= 256) iy = 510 - iy;
        iyo[j] = iy << 8;
    }
    float acc[4][8];
#pragma unroll
    for (int oc = 0; oc < 8; ++oc) {
        float bv = bias[oc0 + oc];
#pragma unroll
        for (int r = 0; r < 4; ++r) acc[r][oc] = bv;
    }
    const int HW = 65536;
#pragma unroll
    for (int ic = 0; ic < 4; ++ic) {
        const float* p = (ic < 3) ? (imgs + (b * 3 + ic) * HW) : (masks + b * HW);
#pragma unroll
        for (int j = 0; j < NR; ++j) {
            float row[K];
#pragma unroll
            for (int kx = 0; kx < K; ++kx) row[kx] = p[iyo[j] + ixo[kx]];
#pragma unroll
            for (int r = 0; r < 4; ++r) {
                const int ky = j - r;
                if (ky >= 0 && ky < K) {
#pragma unroll
                    for (int oc = 0; oc < 8; ++oc) {
                        const float* wc = w + ((oc0 + oc) * 4 + ic) * 49 + ky * K;
#pragma unroll
                        for (int kx = 0; kx < K; ++kx)
                            acc[r][oc] = fmaf(wc[kx], row[kx], acc[r][oc]);
                    }
                }
            }
        }
    }
#pragma unroll
    for (int r = 0; r < 4; ++r) {
        long o = ((long)(b * 260 + oy0 + r + 2) * 260 + ox + 2) * 32 + oc0;
        u16x8 hv, lv;
#pragma unroll
        for (int oc = 0; oc < 8; ++oc) {
            float v = fmaxf(acc[r][oc], 0.f);
            ushort_t h, l;
            split16(v, h, l);
            hv[oc] = h; lv[oc] = l;
        }
        *(u16x8*)&Oh[o] = hv;
        *(u16x8*)&Ol[o] = lv;
    }
}

// ------- MFMA conv (split-fp16), LDS-staged weights + input ----------
// tile: MT oc x NPX px; waves 2x2 (wm: oc half, wn: px half)
template<int K, int S, int CIN, int CSTG, int MT, int NPX, bool WRITE_CL>
__global__ __launch_bounds__(256, 2) void conv_mfma_k(
    const ushort_t* __restrict__ Xh, const ushort_t* __restrict__ Xl,
    const ushort_t* __restrict__ Wh, const ushort_t* __restrict__ Wl,
    const float* __restrict__ bias,
    int Hp, int Wp, int CoutT,
    ushort_t* __restrict__ Oh, ushort_t* __restrict__ Ol, int Hpn, int Wpn, int NP,
    float* __restrict__ Ofp)
{
    constexpr int WS = (NPX - 1) * S + K;
    constexpr int BST = CSTG + 8;
    constexpr int MF = MT / 32;                 // m-frags per wave
    constexpr int NF = NPX / 32;                // n-frags per wave
    constexpr int IN_ELE = WS * BST;
    constexpr int W_ELE = K * MT * BST;
    __shared__ ushort_t Bsh[IN_ELE];
    __shared__ ushort_t Bsl[IN_ELE];
    __shared__ ushort_t Ash[W_ELE];
    __shared__ ushort_t Asl[W_ELE];
    const int tid = threadIdx.x, lane = tid & 63, wid = tid >> 6;
    const int wm = wid & 1, wn = wid >> 1, l15 = lane & 15, quad = lane >> 4;
    const int bx = blockIdx.x, oy = blockIdx.y;
    const int NOC = CoutT / MT;
    const int ocg = blockIdx.z % NOC, b = blockIdx.z / NOC;
    const int ox0 = bx * NPX;

    f32x4 acc[MF][NF];
#pragma unroll
    for (int mi = 0; mi < MF; ++mi)
#pragma unroll
        for (int ni = 0; ni < NF; ++ni) acc[mi][ni] = (f32x4){0.f, 0.f, 0.f, 0.f};

#pragma unroll
    for (int ky = 0; ky < K; ++ky) {
        const long rowoff = ((long)(b * Hp + oy * S + ky) * Wp + ox0 * S) * CIN;
        for (int cs = 0; cs < CIN; cs += CSTG) {
            __syncthreads();                    // WAR: prior phase reads done
            // ---- stage input rows [WS][CSTG] h/l
            constexpr int NCH = WS * CSTG / 8;
#pragma unroll
            for (int it = 0; it < (NCH + 255) / 256; ++it) {
                int flat = tid + it * 256;
                if (flat < NCH) {
                    int e0 = flat * 8;
                    int x = e0 / CSTG;
                    int c = e0 - x * CSTG;
                    *(int4*)&Bsh[x * BST + c] = *(const int4*)&Xh[rowoff + (long)x * CIN + cs + c];
                    *(int4*)&Bsl[x * BST + c] = *(const int4*)&Xl[rowoff + (long)x * CIN + cs + c];
                }
            }
            // ---- stage weights [K kx][MT oc][CSTG ic] h/l for this (ky,cs)
            constexpr int NW = K * MT * CSTG / 8;
#pragma unroll
            for (int it = 0; it < (NW + 255) / 256; ++it) {
                int flat = tid + it * 256;
                if (flat < NW) {
                    int e0 = flat * 8;
                    int kx = e0 / (MT * CSTG);
                    int rem = e0 - kx * MT * CSTG;
                    int oc = rem / CSTG;
                    int ic = rem - oc * CSTG;
                    long src = ((long)((ky * K + kx) * CoutT + ocg * MT + oc)) * CIN + cs + ic;
                    *(int4*)&Ash[(kx * MT + oc) * BST + ic] = *(const int4*)&Wh[src];
                    *(int4*)&Asl[(kx * MT + oc) * BST + ic] = *(const int4*)&Wl[src];
                }
            }
            __syncthreads();
            // ---- inner: all operands from LDS
#pragma unroll
            for (int kx = 0; kx < K; ++kx) {
#pragma unroll
                for (int ic0 = 0; ic0 < CSTG; ic0 += 32) {
                    half8 Ah[MF], Al[MF], Bh[NF], Bl[NF];
#pragma unroll
                    for (int mi = 0; mi < MF; ++mi) {
                        int ao = (kx * MT + wm * (MT / 2) + mi * 16 + l15) * BST + ic0 + quad * 8;
                        Ah[mi] = *(const half8*)&Ash[ao];
                        Al[mi] = *(const half8*)&Asl[ao];
                    }
#pragma unroll
                    for (int ni = 0; ni < NF; ++ni) {
                        int xl = (wn * (NPX / 2) + ni * 16 + l15) * S + kx;
                        Bh[ni] = *(const half8*)&Bsh[xl * BST + ic0 + quad * 8];
                        Bl[ni] = *(const half8*)&Bsl[xl * BST + ic0 + quad * 8];
                    }
#pragma unroll
                    for (int mi = 0; mi < MF; ++mi)
#pragma unroll
                        for (int ni = 0; ni < NF; ++ni) {
                            acc[mi][ni] = __builtin_amdgcn_mfma_f32_16x16x32_f16(Ah[mi], Bh[ni], acc[mi][ni], 0, 0, 0);
                            acc[mi][ni] = __builtin_amdgcn_mfma_f32_16x16x32_f16(Al[mi], Bh[ni], acc[mi][ni], 0, 0, 0);
                            acc[mi][ni] = __builtin_amdgcn_mfma_f32_16x16x32_f16(Ah[mi], Bl[ni], acc[mi][ni], 0, 0, 0);
                        }
                }
            }
        }
    }
    // epilogue: bias + relu, write
#pragma unroll
    for (int ni = 0; ni < NF; ++ni) {
        const int n = ox0 + wn * (NPX / 2) + ni * 16 + l15;
#pragma unroll
        for (int mi = 0; mi < MF; ++mi) {
            const int ocf = ocg * MT + wm * (MT / 2) + mi * 16 + quad * 4;
            float4 bv = *(const float4*)&bias[ocf];
            float v0 = fmaxf(acc[mi][ni][0] + bv.x, 0.f);
            float v1 = fmaxf(acc[mi][ni][1] + bv.y, 0.f);
            float v2 = fmaxf(acc[mi][ni][2] + bv.z, 0.f);
            float v3 = fmaxf(acc[mi][ni][3] + bv.w, 0.f);
            if (WRITE_CL) {
                long o = ((long)(b * Hpn + oy + NP) * Wpn + n + NP) * CoutT + ocf;
                u16x4 hv, lv;
                ushort_t th, tl;
                split16(v0, th, tl); hv[0] = th; lv[0] = tl;
                split16(v1, th, tl); hv[1] = th; lv[1] = tl;
                split16(v2, th, tl); hv[2] = th; lv[2] = tl;
                split16(v3, th, tl); hv[3] = th; lv[3] = tl;
                *(u16x4*)&Oh[o] = hv;
                *(u16x4*)&Ol[o] = lv;
            } else {
                long o = ((long)(b * CoutT + ocf) << 12) + (oy << 6) + n;
                Ofp[o] = v0;
                Ofp[o + 4096] = v1;
                Ofp[o + 8192] = v2;
                Ofp[o + 12288] = v3;
            }
        }
    }
}

// -------- conv5 (256->1, K3 S1 P1) + relu + gate ----------
__global__ __launch_bounds__(256) void conv5_gate_k(
    const float* __restrict__ s4, const float* __restrict__ w,
    const float* __restrict__ bias, float* __restrict__ gate)
{
    const int tid = threadIdx.x;
    const int lane = tid & 63, g = tid >> 6;
    const int oy = blockIdx.x, b = blockIdx.y;
    int ixo[3], iyo[3];
#pragma unroll
    for (int k = 0; k < 3; ++k) {
        int ix = lane + k - 1; if (ix < 0) ix = -ix; if (ix >= 64) ix = 126 - ix;
        int iy = oy + k - 1; if (iy < 0) iy = -iy; if (iy >= 64) iy = 126 - iy;
        ixo[k] = ix; iyo[k] = iy << 6;
    }
    float part = 0.f;
    const float* inb = s4 + ((long)b * 256 + g * 64) * 4096;
    const float* wg = w + g * 64 * 9;
    for (int ic = 0; ic < 64; ++ic) {
        const float* inc = inb + ic * 4096;
        const float* wc = wg + ic * 9;
#pragma unroll
        for (int ky = 0; ky < 3; ++ky)
#pragma unroll
            for (int kx = 0; kx < 3; ++kx)
                part = fmaf(wc[ky * 3 + kx], inc[iyo[ky] + ixo[kx]], part);
    }
    __shared__ float red[4][64];
    red[g][lane] = part;
    __syncthreads();
    if (tid < 64) {
        float s = bias[0] + red[0][tid] + red[1][tid] + red[2][tid] + red[3][tid];
        s = fmaxf(s, 0.f);
        gate[(b << 12) + (oy << 6) + tid] = tanf(PI_F * (tanhf(s) - 0.5f));
    }
}

// ---------------- invn[b][p] = 1/sqrt(sum_c (F+1e-7)^2) ----------------
__global__ __launch_bounds__(256) void invn_k(const float* __restrict__ F, float* __restrict__ invn)
{
    const int p = blockIdx.x * 256 + threadIdx.x;
    const int b = blockIdx.y;
    const float* Fb = F + (long)b * 524288;
    float ss = 0.f;
#pragma unroll 8
    for (int c = 0; c < 128; ++c) {
        float v = Fb[c * 4096 + p] + 1e-7f;
        ss = fmaf(v, v, ss);
    }
    invn[(b << 12) + p] = 1.0f / sqrtf(ss);
}

// -------- prep: Fo16[b][c][p] = bf16(F), Ft16[b][p][c] = bf16(F^T) ---------------
__global__ __launch_bounds__(256) void prep_bf16_k(
    const float* __restrict__ F, ushort_t* __restrict__ Fo16, ushort_t* __restrict__ Ft16)
{
    __shared__ float Ls[128][65];
    const int tid = threadIdx.x;
    const int lane = tid & 63, wv = tid >> 6;
    const int p0 = blockIdx.x * 64, b = blockIdx.y;
#pragma unroll 8
    for (int cc = 0; cc < 32; ++cc) {
        int c = wv * 32 + cc;
        long idx = ((long)b * 128 + c) * 4096 + p0 + lane;
        float v = F[idx];
        Fo16[idx] = f2bf(v);
        Ls[c][lane] = v;
    }
    __syncthreads();
#pragma unroll 8
    for (int i = 0; i < 32; ++i) {
        int flat = tid + 256 * i;
        int c = flat & 127, pl_ = flat >> 7;
        Ft16[((long)b * 4096 + p0 + pl_) * 128 + c] = f2bf(Ls[c][pl_]);
    }
}

// -------- flash attention: per block = 64 q cols, online softmax over 4096 p ----
__global__ __launch_bounds__(256) void flash_attn_k(
    const ushort_t* __restrict__ Ft16, const ushort_t* __restrict__ Fo16,
    const float* __restrict__ invn, const float* __restrict__ gate,
    float* __restrict__ att)
{
    __shared__ float m_run[64], l_run[64], alphaS[64];
    __shared__ float redM[4][64], redS[4][64];
    __shared__ ushort_t Es[64][72];
    const int tid = threadIdx.x, lane = tid & 63, w = tid >> 6;
    const int l15 = lane & 15, quad = lane >> 4;
    const int q0 = blockIdx.x * 64, b = blockIdx.y;
    const int bp = b << 12;
    const ushort_t* Ftb = Ft16 + (long)b * 4096 * 128;
    const ushort_t* Fob = Fo16 + (long)b * 128 * 4096;

    short8 Bq[4][4];
#pragma unroll
    for (int ni = 0; ni < 4; ++ni)
#pragma unroll
        for (int cs = 0; cs < 4; ++cs)
            Bq[ni][cs] = *(const short8*)&Ftb[(long)(q0 + ni * 16 + l15) * 128 + cs * 32 + quad * 8];

    f32x4 O[2][4];
#pragma unroll
    for (int mi = 0; mi < 2; ++mi)
#pragma unroll
        for (int ni = 0; ni < 4; ++ni) O[mi][ni] = (f32x4){0.f, 0.f, 0.f, 0.f};
    if (tid < 64) { m_run[tid] = -3.4e38f; l_run[tid] = 0.f; }

    for (int p0 = 0; p0 < 4096; p0 += 64) {
        __syncthreads();
        f32x4 Sa[4];
#pragma unroll
        for (int ni = 0; ni < 4; ++ni) Sa[ni] = (f32x4){0.f, 0.f, 0.f, 0.f};
#pragma unroll
        for (int cs = 0; cs < 4; ++cs) {
            short8 Ap = *(const short8*)&Ftb[(long)(p0 + w * 16 + l15) * 128 + cs * 32 + quad * 8];
#pragma unroll
            for (int ni = 0; ni < 4; ++ni)
                Sa[ni] = __builtin_amdgcn_mfma_f32_16x16x32_bf16(Ap, Bq[ni][cs], Sa[ni], 0, 0, 0);
        }
        float4 iv = *(const float4*)&invn[bp + p0 + w * 16 + quad * 4];
        float4 gt = *(const float4*)&gate[bp + p0 + w * 16 + quad * 4];
        float mx[4];
#pragma unroll
        for (int ni = 0; ni < 4; ++ni) {
            Sa[ni][0] = fmaf(Sa[ni][0], iv.x, gt.x);
            Sa[ni][1] = fmaf(Sa[ni][1], iv.y, gt.y);
            Sa[ni][2] = fmaf(Sa[ni][2], iv.z, gt.z);
            Sa[ni][3] = fmaf(Sa[ni][3], iv.w, gt.w);
            float m = fmaxf(fmaxf(Sa[ni][0], Sa[ni][1]), fmaxf(Sa[ni][2], Sa[ni][3]));
            m = fmaxf(m, __shfl_xor(m, 16));
            m = fmaxf(m, __shfl_xor(m, 32));
            mx[ni] = m;
        }
        if (quad == 0)
#pragma unroll
            for (int ni = 0; ni < 4; ++ni) redM[w][ni * 16 + l15] = mx[ni];
        __syncthreads();
        if (tid < 64) {
            float mt = fmaxf(fmaxf(redM[0][tid], redM[1][tid]), fmaxf(redM[2][tid], redM[3][tid]));
            float mo = m_run[tid];
            float mn = fmaxf(mo, mt);
            alphaS[tid] = __expf(mo - mn);
            m_run[tid] = mn;
        }
        __syncthreads();
        float sm[4];
#pragma unroll
        for (int ni = 0; ni < 4; ++ni) {
            float mn = m_run[ni * 16 + l15];
            float e0 = __expf(Sa[ni][0] - mn);
            float e1 = __expf(Sa[ni][1] - mn);
            float e2 = __expf(Sa[ni][2] - mn);
            float e3 = __expf(Sa[ni][3] - mn);
            u16x4 ev; ev[0] = f2bf(e0); ev[1] = f2bf(e1); ev[2] = f2bf(e2); ev[3] = f2bf(e3);
            *(u16x4*)&Es[ni * 16 + l15][w * 16 + quad * 4] = ev;
            float sl = (e0 + e1) + (e2 + e3);
            sl += __shfl_xor(sl, 16);
            sl += __shfl_xor(sl, 32);
            sm[ni] = sl;
        }
        if (quad == 0)
#pragma unroll
            for (int ni = 0; ni < 4; ++ni) redS[w][ni * 16 + l15] = sm[ni];
        __syncthreads();
        if (tid < 64)
            l_run[tid] = l_run[tid] * alphaS[tid] +
                         ((redS[0][tid] + redS[1][tid]) + (redS[2][tid] + redS[3][tid]));
        float al[4];
#pragma unroll
        for (int ni = 0; ni < 4; ++ni) al[ni] = alphaS[ni * 16 + l15];
#pragma unroll
        for (int mi = 0; mi < 2; ++mi)
#pragma unroll
            for (int ni = 0; ni < 4; ++ni) {
                O[mi][ni][0] *= al[ni]; O[mi][ni][1] *= al[ni];
                O[mi][ni][2] *= al[ni]; O[mi][ni][3] *= al[ni];
            }
#pragma unroll
        for (int ks = 0; ks < 2; ++ks) {
            short8 Ac[2], Be[4];
#pragma unroll
            for (int mi = 0; mi < 2; ++mi)
                Ac[mi] = *(const short8*)&Fob[(long)(w * 32 + mi * 16 + l15) * 4096 + p0 + ks * 32 + quad * 8];
#pragma unroll
            for (int ni = 0; ni < 4; ++ni)
                Be[ni] = *(const short8*)&Es[ni * 16 + l15][ks * 32 + quad * 8];
#pragma unroll
            for (int mi = 0; mi < 2; ++mi)
#pragma unroll
                for (int ni = 0; ni < 4; ++ni)
                    O[mi][ni] = __builtin_amdgcn_mfma_f32_16x16x32_bf16(Ac[mi], Be[ni], O[mi][ni], 0, 0, 0);
        }
    }
    __syncthreads();
    float il[4];
#pragma unroll
    for (int ni = 0; ni < 4; ++ni) il[ni] = 1.0f / l_run[ni * 16 + l15];
#pragma unroll
    for (int mi = 0; mi < 2; ++mi)
#pragma unroll
        for (int ni = 0; ni < 4; ++ni) {
            int c = w * 32 + mi * 16 + quad * 4;
            int q = q0 + ni * 16 + l15;
#pragma unroll
            for (int r = 0; r < 4; ++r)
                att[((long)(b * 128 + c + r) << 12) + q] = O[mi][ni][r] * il[ni];
        }
}

// ---------------- combiner, all batches ----------------
__global__ __launch_bounds__(256) void combiner_k(
    const float* __restrict__ att, const float* __restrict__ F,
    const float* __restrict__ cw, const float* __restrict__ cb,
    float* __restrict__ out)
{
    const int tid = threadIdx.x;
    const int q = blockIdx.x * 256 + tid;
    const int o0 = blockIdx.y << 4;
    const int b = blockIdx.z;
    const float* Ab = att + (long)b * 524288 + q;
    const float* Fb = F + (long)b * 524288 + q;
    float acc[16];
#pragma unroll
    for (int j = 0; j < 16; ++j) acc[j] = cb[o0 + j];
    for (int c = 0; c < 128; ++c) {
        float a = Ab[(long)c * 4096];
        float f = Fb[(long)c * 4096];
#pragma unroll
        for (int j = 0; j < 16; ++j) {
            acc[j] = fmaf(cw[(o0 + j) * 256 + c], a, acc[j]);
            acc[j] = fmaf(cw[(o0 + j) * 256 + 128 + c], f, acc[j]);
        }
    }
#pragma unroll
    for (int j = 0; j < 16; ++j)
        out[((long)(b * 128 + o0 + j) << 12) + q] = acc[j];
}

// =====================================================================================
extern "C" void kernel_launch(void* const* d_in, const int* in_sizes, int n_in,
                              void* d_out, int out_size, void* d_ws, size_t ws_size,
                              hipStream_t stream)
{
    const float* F     = (const float*)d_in[0];
    const float* imgs  = (const float*)d_in[1];
    const float* masks = (const float*)d_in[2];
    const float* gw1 = (const float*)d_in[3];  const float* gb1 = (const float*)d_in[4];
    const float* gw2 = (const float*)d_in[5];  const float* gb2 = (const float*)d_in[6];
    const float* gw3 = (const float*)d_in[7];  const float* gb3 = (const float*)d_in[8];
    const float* gw4 = (const float*)d_in[9];  const float* gb4 = (const float*)d_in[10];
    const float* gw5 = (const float*)d_in[11]; const float* gb5 = (const float*)d_in[12];
    const float* cw  = (const float*)d_in[13]; const float* cb  = (const float*)d_in[14];
    float* out = (float*)d_out;

    // ---- workspace layout (float offsets), ~142 MB ----
    float* W = (float*)d_ws;
    ushort_t* Xcl2h = (ushort_t*)(W);                 // [8][260][260][32] fp16
    ushort_t* Xcl2l = (ushort_t*)(W + 8652800);
    ushort_t* Xcl4h = (ushort_t*)(W);                 // [8][130][130][128] fp16
    ushort_t* Xcl4l = (ushort_t*)(W + 8652800);
    ushort_t* Xcl3h = (ushort_t*)(W + 17305600);      // [8][132][132][64] fp16
    ushort_t* Xcl3l = (ushort_t*)(W + 21766144);
    ushort_t* Fo16  = (ushort_t*)(W + 17305600);      // [8][128][4096] bf16 (after conv3)
    float*    s4   = W + 26226688;                    // [8][256][64][64] f32
    float*    att  = W + 26226688;                    // [8][128][4096] f32 (after conv5)
    ushort_t* Ft16 = (ushort_t*)(W + 30420992);       // [8][4096][128] bf16 (after conv5)
    ushort_t* W2h = (ushort_t*)(W + 34615296);
    ushort_t* W2l = (ushort_t*)(W + 34640896);
    ushort_t* W3h = (ushort_t*)(W + 34666496);
    ushort_t* W3l = (ushort_t*)(W + 34768896);
    ushort_t* W4h = (ushort_t*)(W + 34871296);
    ushort_t* W4l = (ushort_t*)(W + 35018752);
    float* gate = W + 35166208;
    float* invn = W + 35198976;

    // ---- weight transforms ----
    transform_w_k<<<dim3(200),  256, 0, stream>>>(gw2, W2h, W2l, 64, 32, 25);
    transform_w_k<<<dim3(800),  256, 0, stream>>>(gw3, W3h, W3l, 128, 64, 25);
    transform_w_k<<<dim3(1152), 256, 0, stream>>>(gw4, W4h, W4l, 256, 128, 9);

    // ---- conv stack ----
    conv1_row_k<<<dim3(4, 16, 32), 256, 0, stream>>>(imgs, masks, gw1, gb1, Xcl2h, Xcl2l);
    pad_cl_k<<<dim3(260, 8), 256, 0, stream>>>(Xcl2h, Xcl2l, 260, 260, 2, 32, 256, 256);
    // conv2: K5 S2 Cin32 Cout64, tile 64oc x 64px
    conv_mfma_k<5, 2, 32, 32, 64, 64, true><<<dim3(2, 128, 8), 256, 0, stream>>>(
        Xcl2h, Xcl2l, W2h, W2l, gb2, 260, 260, 64, Xcl3h, Xcl3l, 132, 132, 2, nullptr);
    pad_cl_k<<<dim3(132, 8), 256, 0, stream>>>(Xcl3h, Xcl3l, 132, 132, 2, 64, 128, 128);
    // conv3: K5 S1 Cin64 Cout128, tile 64oc x 128px (NOC=2)
    conv_mfma_k<5, 1, 64, 32, 64, 128, true><<<dim3(1, 128, 16), 256, 0, stream>>>(
        Xcl3h, Xcl3l, W3h, W3l, gb3, 132, 132, 128, Xcl4h, Xcl4l, 130, 130, 1, nullptr);
    pad_cl_k<<<dim3(130, 8), 256, 0, stream>>>(Xcl4h, Xcl4l, 130, 130, 1, 128, 128, 128);
    // conv4: K3 S2 Cin128 Cout256, tile 64oc x 64px (NOC=4)
    conv_mfma_k<3, 2, 128, 32, 64, 64, false><<<dim3(1, 64, 32), 256, 0, stream>>>(
        Xcl4h, Xcl4l, W4h, W4l, gb4, 130, 130, 256, nullptr, nullptr, 0, 0, 0, s4);
    conv5_gate_k<<<dim3(64, 8), 256, 0, stream>>>(s4, gw5, gb5, gate);

    // ---- attention ----
    invn_k<<<dim3(16, 8), 256, 0, stream>>>(F, invn);
    prep_bf16_k<<<dim3(64, 8), 256, 0, stream>>>(F, Fo16, Ft16);
    flash_attn_k<<<dim3(64, 8), 256, 0, stream>>>(Ft16, Fo16, invn, gate, att);
    combiner_k<<<dim3(16, 8, 8), 256, 0, stream>>>(att, F, cw, cb, out);
}